// Round 5
// baseline (934.674 us; speedup 1.0000x reference)
//
#include <hip/hip_runtime.h>
#include <math.h>

#define BATCH    2
#define SEQ      4096
#define DMODEL   2048
#define DSTATE   64
#define HEADDIM  128
#define NHEADS   32
#define DINNER   4096
#define CONVDIM  4224
#define DINPROJ  8352
#define NCHUNK   16
#define CHUNKL   256
#define ROWS     (BATCH*SEQ)   // 8192

typedef __attribute__((ext_vector_type(8))) __bf16 bf16x8;
typedef __attribute__((ext_vector_type(4))) float floatx4;
typedef __attribute__((ext_vector_type(8))) unsigned short ushort8;

__device__ __forceinline__ unsigned short f2bf(float f) {
    union { float f; unsigned int u; } v; v.f = f;
    unsigned int u = v.u;
    unsigned int r = (u + 0x7FFFu + ((u >> 16) & 1u)) >> 16;
    return (unsigned short)r;
}
__device__ __forceinline__ float bf2f(unsigned short s) {
    union { unsigned int u; float f; } v; v.u = ((unsigned int)s) << 16;
    return v.f;
}

__device__ __forceinline__ void gload_lds16(const unsigned short* g, unsigned short* lds) {
    __builtin_amdgcn_global_load_lds(
        (const __attribute__((address_space(1))) unsigned int*)g,
        (__attribute__((address_space(3))) unsigned int*)lds,
        16, 0, 0);
}

// ---------------- fp32 -> bf16 convert ----------------
__global__ __launch_bounds__(256) void f32_to_bf16_k(
    const float* __restrict__ s, unsigned short* __restrict__ d)
{
    int i = (blockIdx.x * 256 + threadIdx.x) * 8;
    float4 a = *reinterpret_cast<const float4*>(s + i);
    float4 b = *reinterpret_cast<const float4*>(s + i + 4);
    ushort8 o;
    o[0] = f2bf(a.x); o[1] = f2bf(a.y); o[2] = f2bf(a.z); o[3] = f2bf(a.w);
    o[4] = f2bf(b.x); o[5] = f2bf(b.y); o[6] = f2bf(b.z); o[7] = f2bf(b.w);
    *reinterpret_cast<ushort8*>(d + i) = o;
}

// ==================== 256x256 8-phase pipelined GEMM v3 ====================
// v3: removed all inline-asm lgkmcnt waits and sched_barrier(0) pins.
// ds_reads are normal loads -> the compiler inserts minimal counted lgkmcnt
// before dependent MFMAs and may interleave reads into MFMA clusters (m97/m141
// lessons). Kept: barriers, counted vmcnt (compiler can't track
// global_load_lds), setprio around MFMA clusters, XOR-swizzled LDS.

#define STAGE(G, ldg, grow0, clampmax, k0, off)                                 \
  { int r0_ = (grow0) + sr0; int r1_ = (grow0) + sr1;                           \
    if ((clampmax) >= 0) { if (r0_ > (clampmax)) r0_ = (clampmax);              \
                           if (r1_ > (clampmax)) r1_ = (clampmax); }            \
    unsigned short* d_ = smem + (off) + ldsw;                                   \
    gload_lds16((G) + (size_t)r0_ * (ldg) + (k0) + sc0, d_);                    \
    gload_lds16((G) + (size_t)r1_ * (ldg) + (k0) + sc1, d_ + 4096); }

__device__ __forceinline__ void rd_a(bf16x8 (&dst)[4][2], const unsigned short* base) {
    #pragma unroll
    for (int mt = 0; mt < 4; ++mt)
        #pragma unroll
        for (int ks = 0; ks < 2; ++ks)
            dst[mt][ks] = *reinterpret_cast<const bf16x8*>(base + (mt * 2 + ks) * 512);
}
__device__ __forceinline__ void rd_b(bf16x8 (&dst)[2][2], const unsigned short* base) {
    #pragma unroll
    for (int nt = 0; nt < 2; ++nt)
        #pragma unroll
        for (int ks = 0; ks < 2; ++ks)
            dst[nt][ks] = *reinterpret_cast<const bf16x8*>(base + (nt * 2 + ks) * 512);
}

template<int R0, int C0>
__device__ __forceinline__ void mfma_q(floatx4 (&acc)[8][4],
                                       const bf16x8 (&a)[4][2],
                                       const bf16x8 (&b)[2][2])
{
    #pragma unroll
    for (int mt = 0; mt < 4; ++mt)
        #pragma unroll
        for (int nt = 0; nt < 2; ++nt) {
            acc[R0+mt][C0+nt] = __builtin_amdgcn_mfma_f32_16x16x32_bf16(a[mt][0], b[nt][0], acc[R0+mt][C0+nt], 0, 0, 0);
            acc[R0+mt][C0+nt] = __builtin_amdgcn_mfma_f32_16x16x32_bf16(a[mt][1], b[nt][1], acc[R0+mt][C0+nt], 0, 0, 0);
        }
}

template<int OUT_BF16>
__global__ __launch_bounds__(512, 2) void gemm256(
    const unsigned short* __restrict__ A, int lda,
    const unsigned short* __restrict__ Bt, int ldb,
    const float* __restrict__ bias,
    void* __restrict__ Cp, int ldc,
    int M, int N, int K)
{
    extern __shared__ __align__(16) unsigned short smem[];
    const int tid  = threadIdx.x;
    const int wave = tid >> 6;
    const int lane = tid & 63;
    const int q    = lane >> 4;
    const int lm   = lane & 15;
    const int wm   = wave >> 2;
    const int wn   = wave & 3;
    const int bh   = wn >> 1;
    const int bn2  = wn & 1;

    const int cpx = gridDim.x >> 3;
    const int sid = (blockIdx.x & 7) * cpx + (blockIdx.x >> 3);
    const int nbm = M >> 8;
    const int bm  = sid % nbm;
    const int bn  = sid / nbm;
    const int arow0 = bm * 256;
    const int brow0 = bn * 256;

    int sr0, sc0, sr1, sc1;
    {
        int L = tid << 4;
        int b = L & 1023; b ^= ((b >> 9) & 1) << 5;
        int sub = L >> 10;
        sr0 = ((sub >> 1) << 4) | (b >> 6);
        sc0 = ((sub & 1) << 5) | ((b & 63) >> 1);
        L = 8192 | (tid << 4);
        b = L & 1023; b ^= ((b >> 9) & 1) << 5;
        sub = L >> 10;
        sr1 = ((sub >> 1) << 4) | (b >> 6);
        sc1 = ((sub & 1) << 5) | ((b & 63) >> 1);
    }
    const int ldsw = wave * 512;
    const int lhw = ((((lm << 6) | (q << 4)) ^ ((lm & 8) << 2)) >> 1);
    const int NT  = K >> 6;
    const int NM1 = N - 1;

    STAGE(A,  lda, arow0,       -1,  0,  0);
    STAGE(A,  lda, arow0 + 128, -1,  0,  8192);
    STAGE(Bt, ldb, brow0,       NM1, 0,  16384);
    STAGE(Bt, ldb, brow0 + 128, NM1, 0,  24576);
    STAGE(Bt, ldb, brow0,       NM1, 64, 32768 + 16384);
    STAGE(Bt, ldb, brow0 + 128, NM1, 64, 32768 + 24576);
    STAGE(A,  lda, arow0,       -1,  64, 32768);
    STAGE(A,  lda, arow0 + 128, -1,  64, 32768 + 8192);
    asm volatile("s_waitcnt vmcnt(8)" ::: "memory");
    __builtin_amdgcn_s_barrier();

    const unsigned short* Ab0 = smem + wm * 8192 + lhw;
    const unsigned short* Bb0 = smem + 16384 + bh * 8192 + bn2 * 4096 + lhw;
    const unsigned short* Ab1 = Ab0 + 32768;
    const unsigned short* Bb1 = Bb0 + 32768;

    bf16x8 a_lo[4][2], a_hi[4][2], b_lo[2][2], b_hi[2][2];
    rd_a(a_lo, Ab0);
    rd_b(b_lo, Bb0);

    floatx4 acc[8][4] = {};
    const int NI = NT >> 1;

    for (int i = 0; i < NI; ++i) {
        int tE2 = 2 * i + 2; if (tE2 > NT - 1) tE2 = NT - 1;
        int tO2 = 2 * i + 3; if (tO2 > NT - 1) tO2 = NT - 1;
        const int kE = tE2 << 6, kO = tO2 << 6;

        // ---- P1: issue qb1(E); MFMA Q00(E) ----
        rd_b(b_hi, Bb0 + 2048);
        __builtin_amdgcn_s_barrier();
        __builtin_amdgcn_s_setprio(1);
        mfma_q<0,0>(acc, a_lo, b_lo);
        __builtin_amdgcn_s_setprio(0);
        __builtin_amdgcn_s_barrier();

        // ---- P2: issue qa1(E); MFMA Q01(E) ----
        rd_a(a_hi, Ab0 + 4096);
        __builtin_amdgcn_s_barrier();
        __builtin_amdgcn_s_setprio(1);
        mfma_q<0,2>(acc, a_lo, b_hi);
        __builtin_amdgcn_s_setprio(0);
        __builtin_amdgcn_s_barrier();

        // ---- P3: stage B(E+2)->buf0; MFMA Q11(E); drain tile O ----
        STAGE(Bt, ldb, brow0,       NM1, kE, 16384);
        STAGE(Bt, ldb, brow0 + 128, NM1, kE, 24576);
        __builtin_amdgcn_s_barrier();
        __builtin_amdgcn_s_setprio(1);
        mfma_q<4,2>(acc, a_hi, b_hi);
        __builtin_amdgcn_s_setprio(0);
        asm volatile("s_waitcnt vmcnt(4)" ::: "memory");
        __builtin_amdgcn_s_barrier();

        // ---- P4: issue qa0(O)+qb0(O); stage A(E+2)->buf0; MFMA Q10(E) ----
        rd_a(a_lo, Ab1);
        rd_b(b_hi, Bb1);
        STAGE(A, lda, arow0,       -1, kE, 0);
        STAGE(A, lda, arow0 + 128, -1, kE, 8192);
        __builtin_amdgcn_s_barrier();
        __builtin_amdgcn_s_setprio(1);
        mfma_q<4,0>(acc, a_hi, b_lo);
        __builtin_amdgcn_s_setprio(0);
        __builtin_amdgcn_s_barrier();

        // ---- P5: issue qb1(O); MFMA Q00(O) ----
        rd_b(b_lo, Bb1 + 2048);
        __builtin_amdgcn_s_barrier();
        __builtin_amdgcn_s_setprio(1);
        mfma_q<0,0>(acc, a_lo, b_hi);
        __builtin_amdgcn_s_setprio(0);
        __builtin_amdgcn_s_barrier();

        // ---- P6: issue qa1(O); MFMA Q01(O) ----
        rd_a(a_hi, Ab1 + 4096);
        __builtin_amdgcn_s_barrier();
        __builtin_amdgcn_s_setprio(1);
        mfma_q<0,2>(acc, a_lo, b_lo);
        __builtin_amdgcn_s_setprio(0);
        __builtin_amdgcn_s_barrier();

        // ---- P7: stage B(O+2)->buf1; MFMA Q11(O); drain tile E+2 ----
        STAGE(Bt, ldb, brow0,       NM1, kO, 32768 + 16384);
        STAGE(Bt, ldb, brow0 + 128, NM1, kO, 32768 + 24576);
        __builtin_amdgcn_s_barrier();
        __builtin_amdgcn_s_setprio(1);
        mfma_q<4,2>(acc, a_hi, b_lo);
        __builtin_amdgcn_s_setprio(0);
        asm volatile("s_waitcnt vmcnt(4)" ::: "memory");
        __builtin_amdgcn_s_barrier();

        // ---- P8: issue qa0(E')+qb0(E'); stage A(O+2)->buf1; MFMA Q10(O) ----
        rd_a(a_lo, Ab0);
        rd_b(b_lo, Bb0);
        STAGE(A, lda, arow0,       -1, kO, 32768);
        STAGE(A, lda, arow0 + 128, -1, kO, 32768 + 8192);
        __builtin_amdgcn_s_barrier();
        __builtin_amdgcn_s_setprio(1);
        mfma_q<4,0>(acc, a_hi, b_hi);
        __builtin_amdgcn_s_setprio(0);
        __builtin_amdgcn_s_barrier();
    }

    asm volatile("s_waitcnt vmcnt(0)" ::: "memory");

    const int row0 = arow0 + wm * 128;
    const int col0 = brow0 + wn * 64;
    #pragma unroll
    for (int mt = 0; mt < 8; ++mt)
        #pragma unroll
        for (int nt = 0; nt < 4; ++nt) {
            int col = col0 + nt * 16 + lm;
            if (col < N) {
                float bv = bias[col];
                #pragma unroll
                for (int r = 0; r < 4; ++r) {
                    int row = row0 + mt * 16 + q * 4 + r;
                    float v = acc[mt][nt][r] + bv;
                    if (OUT_BF16)
                        ((unsigned short*)Cp)[(size_t)row * ldc + col] = f2bf(v);
                    else
                        ((float*)Cp)[(size_t)row * ldc + col] = v;
                }
            }
        }
}

// ---------------- causal depthwise conv (w=4) + bias + SiLU, vectorized ----------------
__global__ __launch_bounds__(256) void conv_silu(
    const unsigned short* __restrict__ zx, const float* __restrict__ conv_w,
    const float* __restrict__ conv_b, unsigned short* __restrict__ xBC)
{
    int idx = blockIdx.x * 256 + threadIdx.x;     // ROWS * (CONVDIM/8) total
    int g   = idx % (CONVDIM / 8);
    int row = idx / (CONVDIM / 8);                // b*SEQ + l
    int l   = row & (SEQ - 1);
    int ch0 = g * 8;
    const unsigned short* base = zx + (size_t)row * DINPROJ + DINNER + ch0;
    float s[8];
    float4 w4[8];
    #pragma unroll
    for (int c = 0; c < 8; ++c) {
        s[c]  = conv_b[ch0 + c];
        w4[c] = *reinterpret_cast<const float4*>(conv_w + (ch0 + c) * 4);
    }
    #pragma unroll
    for (int j = 0; j < 4; ++j) {
        int lj = l - 3 + j;
        if (lj >= 0) {
            ushort8 v = *reinterpret_cast<const ushort8*>(base + (long)(lj - l) * DINPROJ);
            #pragma unroll
            for (int c = 0; c < 8; ++c) {
                float wj = (j == 0) ? w4[c].x : (j == 1) ? w4[c].y : (j == 2) ? w4[c].z : w4[c].w;
                s[c] += wj * bf2f(v[c]);
            }
        }
    }
    ushort8 o;
    #pragma unroll
    for (int c = 0; c < 8; ++c) {
        float sig = 1.f / (1.f + __expf(-s[c]));
        o[c] = f2bf(s[c] * sig);
    }
    *reinterpret_cast<ushort8*>(xBC + (size_t)row * CONVDIM + ch0) = o;
}

// -------- fused: dt=softplus(raw+bias), adt=-exp(A_log)*dt, per-chunk cumsum --------
__global__ __launch_bounds__(256) void dtcum_kernel(
    const unsigned short* __restrict__ zx, const float* __restrict__ dt_bias,
    const float* __restrict__ A_log, float* __restrict__ dtb,
    float* __restrict__ cum, float* __restrict__ csum)
{
    int id = blockIdx.x;
    int h  = id & 31;
    int c  = (id >> 5) & 15;
    int b  = id >> 9;
    int t  = threadIdx.x;
    int row = b * SEQ + c * CHUNKL + t;
    float v = bf2f(zx[(size_t)row * DINPROJ + DINNER + CONVDIM + h]) + dt_bias[h];
    float dtv = (v > 20.f) ? v : log1pf(__expf(v));
    dtb[row * NHEADS + h] = dtv;
    float adt = -__expf(A_log[h]) * dtv;
    __shared__ float s[256];
    s[t] = adt;
    __syncthreads();
    for (int off = 1; off < 256; off <<= 1) {
        float x = (t >= off) ? s[t - off] : 0.f;
        __syncthreads();
        s[t] += x;
        __syncthreads();
    }
    cum[id * 256 + t] = s[t];
    if (t == 255) csum[id] = s[255];
}

// ---------------- scores: S_raw[bc][l][s] = C[l].B[s] (head-independent) ----------------
__global__ __launch_bounds__(256) void score_kernel(
    const unsigned short* __restrict__ xBC, unsigned short* __restrict__ S_raw)
{
    int bc = blockIdx.x;        // 0..63 = b*16+c
    int sq = blockIdx.y;        // 0..3 s-quadrant
    int tid = threadIdx.x;
    int wave = tid >> 6, lane = tid & 63, q = lane >> 4, lm = lane & 15;
    __shared__ __align__(16) unsigned short Ct[256 * 72];
    __shared__ __align__(16) unsigned short Btl[64 * 72];

    #pragma unroll
    for (int i = 0; i < 8; ++i) {
        int idx = tid + 256 * i;
        int r = idx >> 3, ch = idx & 7;
        ushort8 v = *reinterpret_cast<const ushort8*>(
            &xBC[(size_t)(bc * 256 + r) * CONVDIM + DINNER + DSTATE + ch * 8]);
        *reinterpret_cast<ushort8*>(&Ct[r * 72 + ch * 8]) = v;
    }
    #pragma unroll
    for (int i = 0; i < 2; ++i) {
        int idx = tid + 256 * i;
        int r = idx >> 3, ch = idx & 7;
        ushort8 v = *reinterpret_cast<const ushort8*>(
            &xBC[(size_t)(bc * 256 + sq * 64 + r) * CONVDIM + DINNER + ch * 8]);
        *reinterpret_cast<ushort8*>(&Btl[r * 72 + ch * 8]) = v;
    }
    __syncthreads();

    floatx4 acc[4][4] = {};
    #pragma unroll
    for (int ks = 0; ks < 2; ++ks) {
        bf16x8 af[4], bfv[4];
        #pragma unroll
        for (int mt = 0; mt < 4; ++mt)
            af[mt] = *reinterpret_cast<const bf16x8*>(&Ct[(wave * 64 + mt * 16 + lm) * 72 + ks * 32 + q * 8]);
        #pragma unroll
        for (int nt = 0; nt < 4; ++nt)
            bfv[nt] = *reinterpret_cast<const bf16x8*>(&Btl[(nt * 16 + lm) * 72 + ks * 32 + q * 8]);
        #pragma unroll
        for (int mt = 0; mt < 4; ++mt)
            #pragma unroll
            for (int nt = 0; nt < 4; ++nt)
                acc[mt][nt] = __builtin_amdgcn_mfma_f32_16x16x32_bf16(af[mt], bfv[nt], acc[mt][nt], 0, 0, 0);
    }

    #pragma unroll
    for (int mt = 0; mt < 4; ++mt)
        #pragma unroll
        for (int nt = 0; nt < 4; ++nt) {
            int l = wave * 64 + mt * 16 + q * 4;
            int s = sq * 64 + nt * 16 + lm;
            #pragma unroll
            for (int r = 0; r < 4; ++r)
                S_raw[(size_t)(bc * 256 + l + r) * 256 + s] = f2bf(acc[mt][nt][r]);
        }
}

// ---------------- chunk states via MFMA ----------------
__global__ __launch_bounds__(256) void states_kernel(
    const unsigned short* __restrict__ xBC, const float* __restrict__ dtb,
    const float* __restrict__ cum, float* __restrict__ states)
{
    int id = blockIdx.x;
    int h  = id & 31;
    int c  = (id >> 5) & 15;
    int b  = id >> 9;
    int tid = threadIdx.x;
    int wave = tid >> 6, lane = tid & 63, q = lane >> 4, lm = lane & 15;

    __shared__ float wls[256];
    __shared__ __align__(16) unsigned short Xs[64 * 136];
    __shared__ __align__(16) unsigned short Bs[64 * 72];

    const int cumbase = id * 256;
    const int row0 = b * SEQ + c * CHUNKL;
    {
        float cumlast = cum[cumbase + 255];
        wls[tid] = __expf(cumlast - cum[cumbase + tid]) * dtb[(row0 + tid) * NHEADS + h];
    }

    floatx4 acc[2][4] = {};

    for (int sc = 0; sc < 4; ++sc) {
        const int s0 = sc * 64;
        __syncthreads();
        // stage Xw [64 s][136]
        #pragma unroll
        for (int i = 0; i < 4; ++i) {
            int idx = tid + 256 * i;
            int sr = idx >> 4, ch = idx & 15;
            int row = row0 + s0 + sr;
            ushort8 v = *reinterpret_cast<const ushort8*>(
                &xBC[(size_t)row * CONVDIM + h * HEADDIM + ch * 8]);
            float w = wls[s0 + sr];
            ushort8 o;
            #pragma unroll
            for (int j = 0; j < 8; ++j) o[j] = f2bf(bf2f(v[j]) * w);
            *reinterpret_cast<ushort8*>(&Xs[sr * 136 + ch * 8]) = o;
        }
        // stage B [64 s][72]
        #pragma unroll
        for (int i = 0; i < 2; ++i) {
            int idx = tid + 256 * i;
            int sr = idx >> 3, ch = idx & 7;
            int row = row0 + s0 + sr;
            ushort8 v = *reinterpret_cast<const ushort8*>(
                &xBC[(size_t)row * CONVDIM + DINNER + ch * 8]);
            *reinterpret_cast<ushort8*>(&Bs[sr * 72 + ch * 8]) = v;
        }
        __syncthreads();
        // MFMA: wave owns p-rows [wave*32, wave*32+32)
        #pragma unroll
        for (int ks = 0; ks < 2; ++ks) {
            bf16x8 af[2], bfv[4];
            #pragma unroll
            for (int mt = 0; mt < 2; ++mt) {
                int p = wave * 32 + mt * 16 + lm;
                ushort8 tmp;
                #pragma unroll
                for (int j = 0; j < 8; ++j)
                    tmp[j] = Xs[(ks * 32 + q * 8 + j) * 136 + p];
                af[mt] = *reinterpret_cast<bf16x8*>(&tmp);
            }
            #pragma unroll
            for (int nt = 0; nt < 4; ++nt) {
                int n = nt * 16 + lm;
                ushort8 tmp;
                #pragma unroll
                for (int j = 0; j < 8; ++j)
                    tmp[j] = Bs[(ks * 32 + q * 8 + j) * 72 + n];
                bfv[nt] = *reinterpret_cast<bf16x8*>(&tmp);
            }
            #pragma unroll
            for (int mt = 0; mt < 2; ++mt)
                #pragma unroll
                for (int nt = 0; nt < 4; ++nt)
                    acc[mt][nt] = __builtin_amdgcn_mfma_f32_16x16x32_bf16(af[mt], bfv[nt], acc[mt][nt], 0, 0, 0);
        }
    }

    #pragma unroll
    for (int mt = 0; mt < 2; ++mt)
        #pragma unroll
        for (int nt = 0; nt < 4; ++nt)
            #pragma unroll
            for (int r = 0; r < 4; ++r) {
                int p = wave * 32 + mt * 16 + q * 4 + r;
                int n = nt * 16 + lm;
                states[(size_t)id * 8192 + p * 64 + n] = acc[mt][nt][r];
            }
}

// ---------------- inter-chunk recurrence (in-place) ----------------
__global__ __launch_bounds__(256) void inter_kernel(
    float* __restrict__ states, const float* __restrict__ csum)
{
    int idx = blockIdx.x * 256 + threadIdx.x;
    int pn  = idx & 8191;
    int h   = (idx >> 13) & 31;
    int b   = idx >> 18;
    float S = 0.f;
    for (int c = 0; c < 16; ++c) {
        int id = (b * 16 + c) * 32 + h;
        size_t off = (size_t)id * 8192 + pn;
        float st = states[off];
        states[off] = S;
        S = S * __expf(csum[id]) + st;
    }
}

// ---------------- Y via MFMA: Y = P.Xdt + (C*efac).interS^T ----------------
// v3: lh split to blockIdx.y (2048 blocks) — halves per-block serial chain,
// doubles block-level parallelism for latency hiding.
__global__ __launch_bounds__(256) void y_mfma(
    const unsigned short* __restrict__ xBC,
    const unsigned short* __restrict__ S_raw,
    const float* __restrict__ dtb,
    const float* __restrict__ cum,
    const float* __restrict__ inter,
    unsigned short* __restrict__ zx)
{
    int id = blockIdx.x;               // (b*16+c)*32 + h
    int h  = id & 31;
    int bc = id >> 5;
    const int lh = blockIdx.y;         // 0/1 l-half
    int tid = threadIdx.x, wave = tid >> 6, lane = tid & 63, q = lane >> 4, lm = lane & 15;
    int wl = wave >> 1, wp = wave & 1;

    __shared__ float cums[256];
    __shared__ float dts[256];
    __shared__ __align__(16) unsigned short XdtT[128 * 72];   // Xs[64][136] or interS[p][72]
    __shared__ __align__(16) unsigned short PT[128 * 72];     // P[128][72]

    cums[tid] = cum[id * 256 + tid];
    dts[tid]  = dtb[(size_t)(bc * 256 + tid) * NHEADS + h];
    __syncthreads();

    floatx4 acc[4][4] = {};
    const int l0w = lh * 128 + wl * 64;
    const int nst = 2 * lh + 2;

    for (int st = 0; st < nst; ++st) {
        const int s0 = st * 64;
        __syncthreads();
        // --- stage Xs: Xdt natural [64 s][136] ---
        #pragma unroll
        for (int i = 0; i < 4; ++i) {
            int idx = tid + 256 * i;
            int sr = idx >> 4, ch = idx & 15;
            int srow = bc * 256 + s0 + sr;
            ushort8 v = *reinterpret_cast<const ushort8*>(
                &xBC[(size_t)srow * CONVDIM + h * HEADDIM + ch * 8]);
            float dt = dts[s0 + sr];
            ushort8 o;
            #pragma unroll
            for (int j = 0; j < 8; ++j) o[j] = f2bf(bf2f(v[j]) * dt);
            *reinterpret_cast<ushort8*>(&XdtT[sr * 136 + ch * 8]) = o;
        }
        // --- P stage: rows r in [r0,128) of this half (decay+mask, bf16) ---
        const int r0 = (s0 > lh * 128) ? 64 : 0;
        const int iters = (128 - r0) >> 5;
        for (int i = 0; i < iters; ++i) {
            int idx = tid + 256 * i;
            int r = r0 + (idx >> 3), ch = idx & 7;
            int l = lh * 128 + r;
            float cl = cums[l];
            ushort8 v = *reinterpret_cast<const ushort8*>(
                &S_raw[(size_t)(bc * 256 + l) * 256 + s0 + ch * 8]);
            ushort8 o;
            #pragma unroll
            for (int j = 0; j < 8; ++j) {
                int s = s0 + ch * 8 + j;
                float val = (s <= l) ? bf2f(v[j]) * __expf(cl - cums[s]) : 0.f;
                o[j] = f2bf(val);
            }
            *reinterpret_cast<ushort8*>(&PT[r * 72 + ch * 8]) = o;
        }
        __syncthreads();
        // --- MFMA (waves with l >= s participate) ---
        if (s0 <= l0w) {
            #pragma unroll
            for (int ks = 0; ks < 2; ++ks) {
                bf16x8 af[4], bfv[4];
                #pragma unroll
                for (int mt = 0; mt < 4; ++mt)
                    af[mt] = *reinterpret_cast<const bf16x8*>(
                        &PT[(wl * 64 + mt * 16 + lm) * 72 + ks * 32 + q * 8]);
                #pragma unroll
                for (int nt = 0; nt < 4; ++nt) {
                    int pcol = wp * 64 + nt * 16 + lm;
                    ushort8 tmp;
                    #pragma unroll
                    for (int j = 0; j < 8; ++j)
                        tmp[j] = XdtT[(ks * 32 + q * 8 + j) * 136 + pcol];
                    bfv[nt] = *reinterpret_cast<bf16x8*>(&tmp);
                }
                #pragma unroll
                for (int mt = 0; mt < 4; ++mt)
                    #pragma unroll
                    for (int nt = 0; nt < 4; ++nt)
                        acc[mt][nt] = __builtin_amdgcn_mfma_f32_16x16x32_bf16(af[mt], bfv[nt], acc[mt][nt], 0, 0, 0);
            }
        }
    }

    // --- virtual tile: Y_off = (C*efac) . interS^T ---
    __syncthreads();
    {
        int p = tid >> 1, n0 = (tid & 1) * 32;
        const float* sp = &inter[(size_t)id * 8192 + p * 64 + n0];
        #pragma unroll
        for (int k2 = 0; k2 < 4; ++k2) {
            float4 a = *reinterpret_cast<const float4*>(sp + k2 * 8);
            float4 b2 = *reinterpret_cast<const float4*>(sp + k2 * 8 + 4);
            ushort8 o;
            o[0] = f2bf(a.x); o[1] = f2bf(a.y); o[2] = f2bf(a.z); o[3] = f2bf(a.w);
            o[4] = f2bf(b2.x); o[5] = f2bf(b2.y); o[6] = f2bf(b2.z); o[7] = f2bf(b2.w);
            *reinterpret_cast<ushort8*>(&XdtT[p * 72 + n0 + k2 * 8]) = o;
        }
        int r = tid >> 1;
        int l = lh * 128 + r;
        float ef = __expf(cums[l]);
        const unsigned short* cp = &xBC[(size_t)(bc * 256 + l) * CONVDIM + DINNER + DSTATE + n0];
        #pragma unroll
        for (int k2 = 0; k2 < 4; ++k2) {
            ushort8 v = *reinterpret_cast<const ushort8*>(cp + k2 * 8);
            ushort8 o;
            #pragma unroll
            for (int j = 0; j < 8; ++j) o[j] = f2bf(bf2f(v[j]) * ef);
            *reinterpret_cast<ushort8*>(&PT[r * 72 + n0 + k2 * 8]) = o;
        }
    }
    __syncthreads();
    #pragma unroll
    for (int ks = 0; ks < 2; ++ks) {
        bf16x8 af[4], bfv[4];
        #pragma unroll
        for (int mt = 0; mt < 4; ++mt)
            af[mt] = *reinterpret_cast<const bf16x8*>(
                &PT[(wl * 64 + mt * 16 + lm) * 72 + ks * 32 + q * 8]);
        #pragma unroll
        for (int nt = 0; nt < 4; ++nt)
            bfv[nt] = *reinterpret_cast<const bf16x8*>(
                &XdtT[(wp * 64 + nt * 16 + lm) * 72 + ks * 32 + q * 8]);
        #pragma unroll
        for (int mt = 0; mt < 4; ++mt)
            #pragma unroll
            for (int nt = 0; nt < 4; ++nt)
                acc[mt][nt] = __builtin_amdgcn_mfma_f32_16x16x32_bf16(af[mt], bfv[nt], acc[mt][nt], 0, 0, 0);
    }

    // --- epilogue: write Y (bf16) into zx y-region ---
    #pragma unroll
    for (int mt = 0; mt < 4; ++mt)
        #pragma unroll
        for (int nt = 0; nt < 4; ++nt) {
            int l = lh * 128 + wl * 64 + mt * 16 + q * 4;
            int pcol = wp * 64 + nt * 16 + lm;
            #pragma unroll
            for (int r = 0; r < 4; ++r)
                zx[(size_t)(bc * 256 + l + r) * DINPROJ + DINNER + h * HEADDIM + pcol]
                    = f2bf(acc[mt][nt][r]);
        }
}

// ---------------- y * silu(z), LayerNorm (vectorized) ----------------
__global__ __launch_bounds__(256) void gate_ln(
    unsigned short* __restrict__ zx, const float* __restrict__ ln_w, const float* __restrict__ ln_b)
{
    int row = blockIdx.x;
    int t   = threadIdx.x;
    size_t base = (size_t)row * DINPROJ;
    int i0 = t * 16;
    ushort8 za = *reinterpret_cast<const ushort8*>(zx + base + i0);
    ushort8 zb = *reinterpret_cast<const ushort8*>(zx + base + i0 + 8);
    ushort8 ya = *reinterpret_cast<const ushort8*>(zx + base + DINNER + i0);
    ushort8 yb = *reinterpret_cast<const ushort8*>(zx + base + DINNER + i0 + 8);
    float g[16];
    float sum = 0.f, sumsq = 0.f;
    #pragma unroll
    for (int j = 0; j < 8; ++j) {
        float z = bf2f(za[j]);
        float y = bf2f(ya[j]);
        float sig = 1.f / (1.f + __expf(-z));
        float v = y * z * sig;
        g[j] = v; sum += v; sumsq += v * v;
    }
    #pragma unroll
    for (int j = 0; j < 8; ++j) {
        float z = bf2f(zb[j]);
        float y = bf2f(yb[j]);
        float sig = 1.f / (1.f + __expf(-z));
        float v = y * z * sig;
        g[8 + j] = v; sum += v; sumsq += v * v;
    }
    __shared__ float rs[256], rq[256];
    rs[t] = sum; rq[t] = sumsq;
    __syncthreads();
    for (int off = 128; off > 0; off >>= 1) {
        if (t < off) { rs[t] += rs[t + off]; rq[t] += rq[t + off]; }
        __syncthreads();
    }
    float mu   = rs[0] * (1.f / DINNER);
    float var  = rq[0] * (1.f / DINNER) - mu * mu;
    float rstd = rsqrtf(var + 1e-5f);
    ushort8 o0, o1;
    #pragma unroll
    for (int j = 0; j < 8; ++j)
        o0[j] = f2bf((g[j] - mu) * rstd * ln_w[i0 + j] + ln_b[i0 + j]);
    #pragma unroll
    for (int j = 0; j < 8; ++j)
        o1[j] = f2bf((g[8 + j] - mu) * rstd * ln_w[i0 + 8 + j] + ln_b[i0 + 8 + j]);
    *reinterpret_cast<ushort8*>(zx + base + DINNER + i0)     = o0;
    *reinterpret_cast<ushort8*>(zx + base + DINNER + i0 + 8) = o1;
}

extern "C" void kernel_launch(void* const* d_in, const int* in_sizes, int n_in,
                              void* d_out, int out_size, void* d_ws, size_t ws_size,
                              hipStream_t stream)
{
    const float* u          = (const float*)d_in[0];
    const float* in_proj_w  = (const float*)d_in[1];
    const float* in_proj_b  = (const float*)d_in[2];
    const float* conv_w     = (const float*)d_in[3];
    const float* conv_b     = (const float*)d_in[4];
    const float* dt_bias    = (const float*)d_in[5];
    const float* A_log      = (const float*)d_in[6];
    const float* ln_w       = (const float*)d_in[7];
    const float* ln_b       = (const float*)d_in[8];
    const float* out_proj_w = (const float*)d_in[9];
    const float* out_proj_b = (const float*)d_in[10];
    float* out = (float*)d_out;

    // workspace layout (~238.5 MiB)
    unsigned short* zx  = (unsigned short*)d_ws;              // ROWS*DINPROJ bf16
    unsigned short* xBC = zx + (size_t)ROWS * DINPROJ;        // ROWS*CONVDIM bf16
    float* dtb    = (float*)(xBC + (size_t)ROWS * CONVDIM);   // ROWS*NHEADS f32
    float* cum    = dtb + (size_t)ROWS * NHEADS;              // ROWS*NHEADS f32
    float* csum   = cum + (size_t)ROWS * NHEADS;              // 1024 f32
    float* states = csum + 1024;                              // 1024*8192 f32
    unsigned short* S_raw = (unsigned short*)(states + (size_t)1024 * 8192); // 64*256*256 bf16

    // aliases (no live overlap):
    unsigned short* u_bf  = (unsigned short*)states;
    unsigned short* w1_bf = xBC;
    unsigned short* w2_bf = (unsigned short*)states;

    static bool attr_done = false;
    if (!attr_done) {
        hipFuncSetAttribute(reinterpret_cast<const void*>(&gemm256<1>),
                            hipFuncAttributeMaxDynamicSharedMemorySize, 131072);
        hipFuncSetAttribute(reinterpret_cast<const void*>(&gemm256<0>),
                            hipFuncAttributeMaxDynamicSharedMemorySize, 131072);
        attr_done = true;
    }

    dim3 blk(256);

    f32_to_bf16_k<<<dim3((ROWS * DMODEL) / 2048), blk, 0, stream>>>(u, u_bf);
    f32_to_bf16_k<<<dim3((DINPROJ * DMODEL) / 2048), blk, 0, stream>>>(in_proj_w, w1_bf);

    // in_proj: M=8192, N=8352, K=2048 -> grid 32*33 = 1056 (%8==0)
    gemm256<1><<<dim3((ROWS / 256) * ((DINPROJ + 255) / 256)), dim3(512), 131072, stream>>>(
        u_bf, DMODEL, w1_bf, DMODEL, in_proj_b, (void*)zx, DINPROJ, ROWS, DINPROJ, DMODEL);

    conv_silu<<<dim3((ROWS * (CONVDIM / 8)) / 256), blk, 0, stream>>>(zx, conv_w, conv_b, xBC);

    dtcum_kernel<<<dim3(BATCH * NCHUNK * NHEADS), blk, 0, stream>>>(zx, dt_bias, A_log, dtb, cum, csum);

    score_kernel<<<dim3(BATCH * NCHUNK, 4), blk, 0, stream>>>(xBC, S_raw);

    states_kernel<<<dim3(BATCH * NCHUNK * NHEADS), blk, 0, stream>>>(xBC, dtb, cum, states);

    inter_kernel<<<dim3((BATCH * NHEADS * 8192) / 256), blk, 0, stream>>>(states, csum);

    y_mfma<<<dim3(BATCH * NCHUNK * NHEADS, 2), blk, 0, stream>>>(xBC, S_raw, dtb, cum, states, zx);

    gate_ln<<<dim3(ROWS), blk, 0, stream>>>(zx, ln_w, ln_b);

    f32_to_bf16_k<<<dim3((DMODEL * DINNER) / 2048), blk, 0, stream>>>(out_proj_w, w2_bf);

    // out_proj: M=8192, N=2048, K=4096 -> grid 32*8 = 256 (%8==0)
    gemm256<0><<<dim3((ROWS / 256) * (DMODEL / 256)), dim3(512), 131072, stream>>>(
        (const unsigned short*)(zx + DINNER), DINPROJ, w2_bf, DINNER, out_proj_b, (void*)out,
        DMODEL, ROWS, DMODEL, DINNER);
}

// Round 6
// 907.268 us; speedup vs baseline: 1.0302x; 1.0302x over previous
//
#include <hip/hip_runtime.h>
#include <math.h>

#define BATCH    2
#define SEQ      4096
#define DMODEL   2048
#define DSTATE   64
#define HEADDIM  128
#define NHEADS   32
#define DINNER   4096
#define CONVDIM  4224
#define DINPROJ  8352
#define NCHUNK   16
#define CHUNKL   256
#define ROWS     (BATCH*SEQ)   // 8192

typedef __attribute__((ext_vector_type(8))) __bf16 bf16x8;
typedef __attribute__((ext_vector_type(4))) float floatx4;
typedef __attribute__((ext_vector_type(8))) unsigned short ushort8;

__device__ __forceinline__ unsigned short f2bf(float f) {
    union { float f; unsigned int u; } v; v.f = f;
    unsigned int u = v.u;
    unsigned int r = (u + 0x7FFFu + ((u >> 16) & 1u)) >> 16;
    return (unsigned short)r;
}
__device__ __forceinline__ float bf2f(unsigned short s) {
    union { unsigned int u; float f; } v; v.u = ((unsigned int)s) << 16;
    return v.f;
}

__device__ __forceinline__ void gload_lds16(const unsigned short* g, unsigned short* lds) {
    __builtin_amdgcn_global_load_lds(
        (const __attribute__((address_space(1))) unsigned int*)g,
        (__attribute__((address_space(3))) unsigned int*)lds,
        16, 0, 0);
}

__device__ __forceinline__ void cvt8(const float* s, unsigned short* d, int i) {
    float4 a = *reinterpret_cast<const float4*>(s + i);
    float4 b = *reinterpret_cast<const float4*>(s + i + 4);
    ushort8 o;
    o[0] = f2bf(a.x); o[1] = f2bf(a.y); o[2] = f2bf(a.z); o[3] = f2bf(a.w);
    o[4] = f2bf(b.x); o[5] = f2bf(b.y); o[6] = f2bf(b.z); o[7] = f2bf(b.w);
    *reinterpret_cast<ushort8*>(d + i) = o;
}

// ---------------- fused fp32 -> bf16 convert (u + in_proj_w) ----------------
__global__ __launch_bounds__(256) void f32_to_bf16_2(
    const float* __restrict__ s0, unsigned short* __restrict__ d0, int nb0,
    const float* __restrict__ s1, unsigned short* __restrict__ d1)
{
    int b = blockIdx.x;
    if (b < nb0) {
        cvt8(s0, d0, (b * 256 + threadIdx.x) * 8);
    } else {
        cvt8(s1, d1, ((b - nb0) * 256 + threadIdx.x) * 8);
    }
}

// ==================== 256x256 8-phase pipelined GEMM ====================
// (frozen: 36% MfmaUtil, 0 bank conflicts — structural ceiling for this
//  1-block/CU 256^2 shape; see R1/R2/R5 null results)

#define STAGE(G, ldg, grow0, clampmax, k0, off)                                 \
  { int r0_ = (grow0) + sr0; int r1_ = (grow0) + sr1;                           \
    if ((clampmax) >= 0) { if (r0_ > (clampmax)) r0_ = (clampmax);              \
                           if (r1_ > (clampmax)) r1_ = (clampmax); }            \
    unsigned short* d_ = smem + (off) + ldsw;                                   \
    gload_lds16((G) + (size_t)r0_ * (ldg) + (k0) + sc0, d_);                    \
    gload_lds16((G) + (size_t)r1_ * (ldg) + (k0) + sc1, d_ + 4096); }

__device__ __forceinline__ void rd_a(bf16x8 (&dst)[4][2], const unsigned short* base) {
    #pragma unroll
    for (int mt = 0; mt < 4; ++mt)
        #pragma unroll
        for (int ks = 0; ks < 2; ++ks)
            dst[mt][ks] = *reinterpret_cast<const bf16x8*>(base + (mt * 2 + ks) * 512);
}
__device__ __forceinline__ void rd_b(bf16x8 (&dst)[2][2], const unsigned short* base) {
    #pragma unroll
    for (int nt = 0; nt < 2; ++nt)
        #pragma unroll
        for (int ks = 0; ks < 2; ++ks)
            dst[nt][ks] = *reinterpret_cast<const bf16x8*>(base + (nt * 2 + ks) * 512);
}

template<int R0, int C0>
__device__ __forceinline__ void mfma_q(floatx4 (&acc)[8][4],
                                       const bf16x8 (&a)[4][2],
                                       const bf16x8 (&b)[2][2])
{
    #pragma unroll
    for (int mt = 0; mt < 4; ++mt)
        #pragma unroll
        for (int nt = 0; nt < 2; ++nt) {
            acc[R0+mt][C0+nt] = __builtin_amdgcn_mfma_f32_16x16x32_bf16(a[mt][0], b[nt][0], acc[R0+mt][C0+nt], 0, 0, 0);
            acc[R0+mt][C0+nt] = __builtin_amdgcn_mfma_f32_16x16x32_bf16(a[mt][1], b[nt][1], acc[R0+mt][C0+nt], 0, 0, 0);
        }
}

template<int OUT_BF16>
__global__ __launch_bounds__(512, 2) void gemm256(
    const unsigned short* __restrict__ A, int lda,
    const unsigned short* __restrict__ Bt, int ldb,
    const float* __restrict__ bias,
    void* __restrict__ Cp, int ldc,
    int M, int N, int K)
{
    extern __shared__ __align__(16) unsigned short smem[];
    const int tid  = threadIdx.x;
    const int wave = tid >> 6;
    const int lane = tid & 63;
    const int q    = lane >> 4;
    const int lm   = lane & 15;
    const int wm   = wave >> 2;
    const int wn   = wave & 3;
    const int bh   = wn >> 1;
    const int bn2  = wn & 1;

    const int cpx = gridDim.x >> 3;
    const int sid = (blockIdx.x & 7) * cpx + (blockIdx.x >> 3);
    const int nbm = M >> 8;
    const int bm  = sid % nbm;
    const int bn  = sid / nbm;
    const int arow0 = bm * 256;
    const int brow0 = bn * 256;

    int sr0, sc0, sr1, sc1;
    {
        int L = tid << 4;
        int b = L & 1023; b ^= ((b >> 9) & 1) << 5;
        int sub = L >> 10;
        sr0 = ((sub >> 1) << 4) | (b >> 6);
        sc0 = ((sub & 1) << 5) | ((b & 63) >> 1);
        L = 8192 | (tid << 4);
        b = L & 1023; b ^= ((b >> 9) & 1) << 5;
        sub = L >> 10;
        sr1 = ((sub >> 1) << 4) | (b >> 6);
        sc1 = ((sub & 1) << 5) | ((b & 63) >> 1);
    }
    const int ldsw = wave * 512;
    const int lhw = ((((lm << 6) | (q << 4)) ^ ((lm & 8) << 2)) >> 1);
    const int NT  = K >> 6;
    const int NM1 = N - 1;

    STAGE(A,  lda, arow0,       -1,  0,  0);
    STAGE(A,  lda, arow0 + 128, -1,  0,  8192);
    STAGE(Bt, ldb, brow0,       NM1, 0,  16384);
    STAGE(Bt, ldb, brow0 + 128, NM1, 0,  24576);
    STAGE(Bt, ldb, brow0,       NM1, 64, 32768 + 16384);
    STAGE(Bt, ldb, brow0 + 128, NM1, 64, 32768 + 24576);
    STAGE(A,  lda, arow0,       -1,  64, 32768);
    STAGE(A,  lda, arow0 + 128, -1,  64, 32768 + 8192);
    asm volatile("s_waitcnt vmcnt(8)" ::: "memory");
    __builtin_amdgcn_s_barrier();

    const unsigned short* Ab0 = smem + wm * 8192 + lhw;
    const unsigned short* Bb0 = smem + 16384 + bh * 8192 + bn2 * 4096 + lhw;
    const unsigned short* Ab1 = Ab0 + 32768;
    const unsigned short* Bb1 = Bb0 + 32768;

    bf16x8 a_lo[4][2], a_hi[4][2], b_lo[2][2], b_hi[2][2];
    rd_a(a_lo, Ab0);
    rd_b(b_lo, Bb0);

    floatx4 acc[8][4] = {};
    const int NI = NT >> 1;

    for (int i = 0; i < NI; ++i) {
        int tE2 = 2 * i + 2; if (tE2 > NT - 1) tE2 = NT - 1;
        int tO2 = 2 * i + 3; if (tO2 > NT - 1) tO2 = NT - 1;
        const int kE = tE2 << 6, kO = tO2 << 6;

        rd_b(b_hi, Bb0 + 2048);
        __builtin_amdgcn_s_barrier();
        __builtin_amdgcn_s_setprio(1);
        mfma_q<0,0>(acc, a_lo, b_lo);
        __builtin_amdgcn_s_setprio(0);
        __builtin_amdgcn_s_barrier();

        rd_a(a_hi, Ab0 + 4096);
        __builtin_amdgcn_s_barrier();
        __builtin_amdgcn_s_setprio(1);
        mfma_q<0,2>(acc, a_lo, b_hi);
        __builtin_amdgcn_s_setprio(0);
        __builtin_amdgcn_s_barrier();

        STAGE(Bt, ldb, brow0,       NM1, kE, 16384);
        STAGE(Bt, ldb, brow0 + 128, NM1, kE, 24576);
        __builtin_amdgcn_s_barrier();
        __builtin_amdgcn_s_setprio(1);
        mfma_q<4,2>(acc, a_hi, b_hi);
        __builtin_amdgcn_s_setprio(0);
        asm volatile("s_waitcnt vmcnt(4)" ::: "memory");
        __builtin_amdgcn_s_barrier();

        rd_a(a_lo, Ab1);
        rd_b(b_hi, Bb1);
        STAGE(A, lda, arow0,       -1, kE, 0);
        STAGE(A, lda, arow0 + 128, -1, kE, 8192);
        __builtin_amdgcn_s_barrier();
        __builtin_amdgcn_s_setprio(1);
        mfma_q<4,0>(acc, a_hi, b_lo);
        __builtin_amdgcn_s_setprio(0);
        __builtin_amdgcn_s_barrier();

        rd_b(b_lo, Bb1 + 2048);
        __builtin_amdgcn_s_barrier();
        __builtin_amdgcn_s_setprio(1);
        mfma_q<0,0>(acc, a_lo, b_hi);
        __builtin_amdgcn_s_setprio(0);
        __builtin_amdgcn_s_barrier();

        rd_a(a_hi, Ab1 + 4096);
        __builtin_amdgcn_s_barrier();
        __builtin_amdgcn_s_setprio(1);
        mfma_q<0,2>(acc, a_lo, b_lo);
        __builtin_amdgcn_s_setprio(0);
        __builtin_amdgcn_s_barrier();

        STAGE(Bt, ldb, brow0,       NM1, kO, 32768 + 16384);
        STAGE(Bt, ldb, brow0 + 128, NM1, kO, 32768 + 24576);
        __builtin_amdgcn_s_barrier();
        __builtin_amdgcn_s_setprio(1);
        mfma_q<4,2>(acc, a_hi, b_lo);
        __builtin_amdgcn_s_setprio(0);
        asm volatile("s_waitcnt vmcnt(4)" ::: "memory");
        __builtin_amdgcn_s_barrier();

        rd_a(a_lo, Ab0);
        rd_b(b_lo, Bb0);
        STAGE(A, lda, arow0,       -1, kO, 32768);
        STAGE(A, lda, arow0 + 128, -1, kO, 32768 + 8192);
        __builtin_amdgcn_s_barrier();
        __builtin_amdgcn_s_setprio(1);
        mfma_q<4,0>(acc, a_hi, b_hi);
        __builtin_amdgcn_s_setprio(0);
        __builtin_amdgcn_s_barrier();
    }

    asm volatile("s_waitcnt vmcnt(0)" ::: "memory");

    const int row0 = arow0 + wm * 128;
    const int col0 = brow0 + wn * 64;
    #pragma unroll
    for (int mt = 0; mt < 8; ++mt)
        #pragma unroll
        for (int nt = 0; nt < 4; ++nt) {
            int col = col0 + nt * 16 + lm;
            if (col < N) {
                float bv = bias[col];
                #pragma unroll
                for (int r = 0; r < 4; ++r) {
                    int row = row0 + mt * 16 + q * 4 + r;
                    float v = acc[mt][nt][r] + bv;
                    if (OUT_BF16)
                        ((unsigned short*)Cp)[(size_t)row * ldc + col] = f2bf(v);
                    else
                        ((float*)Cp)[(size_t)row * ldc + col] = v;
                }
            }
        }
}

// ------- fused: causal depthwise conv + SiLU  AND  dt softplus + chunk cumsum -------
// blocks [0, NCONVB): conv_silu; blocks [NCONVB, NCONVB+1024): dtcum with
// wave-shuffle scan (replaces 16-barrier Hillis-Steele ladder).
#define NCONVB (ROWS * (CONVDIM / 8) / 256)   // 16896

__global__ __launch_bounds__(256) void convdt(
    const unsigned short* __restrict__ zx, const float* __restrict__ conv_w,
    const float* __restrict__ conv_b, unsigned short* __restrict__ xBC,
    const float* __restrict__ dt_bias, const float* __restrict__ A_log,
    float* __restrict__ dtb, float* __restrict__ cum, float* __restrict__ csum)
{
    __shared__ float ws4[4];
    if (blockIdx.x < NCONVB) {
        int idx = blockIdx.x * 256 + threadIdx.x;
        int g   = idx % (CONVDIM / 8);
        int row = idx / (CONVDIM / 8);
        int l   = row & (SEQ - 1);
        int ch0 = g * 8;
        const unsigned short* base = zx + (size_t)row * DINPROJ + DINNER + ch0;
        float s[8];
        float4 w4[8];
        #pragma unroll
        for (int c = 0; c < 8; ++c) {
            s[c]  = conv_b[ch0 + c];
            w4[c] = *reinterpret_cast<const float4*>(conv_w + (ch0 + c) * 4);
        }
        #pragma unroll
        for (int j = 0; j < 4; ++j) {
            int lj = l - 3 + j;
            if (lj >= 0) {
                ushort8 v = *reinterpret_cast<const ushort8*>(base + (long)(lj - l) * DINPROJ);
                #pragma unroll
                for (int c = 0; c < 8; ++c) {
                    float wj = (j == 0) ? w4[c].x : (j == 1) ? w4[c].y : (j == 2) ? w4[c].z : w4[c].w;
                    s[c] += wj * bf2f(v[c]);
                }
            }
        }
        ushort8 o;
        #pragma unroll
        for (int c = 0; c < 8; ++c) {
            float sig = 1.f / (1.f + __expf(-s[c]));
            o[c] = f2bf(s[c] * sig);
        }
        *reinterpret_cast<ushort8*>(xBC + (size_t)row * CONVDIM + ch0) = o;
    } else {
        int id = blockIdx.x - NCONVB;
        int h  = id & 31;
        int c  = (id >> 5) & 15;
        int b  = id >> 9;
        int t  = threadIdx.x;
        int row = b * SEQ + c * CHUNKL + t;
        float v = bf2f(zx[(size_t)row * DINPROJ + DINNER + CONVDIM + h]) + dt_bias[h];
        float dtv = (v > 20.f) ? v : log1pf(__expf(v));
        dtb[row * NHEADS + h] = dtv;
        float adt = -__expf(A_log[h]) * dtv;
        int lane = t & 63, wv = t >> 6;
        float s = adt;
        #pragma unroll
        for (int o = 1; o < 64; o <<= 1) {
            float x = __shfl_up(s, o, 64);
            if (lane >= o) s += x;
        }
        if (lane == 63) ws4[wv] = s;
        __syncthreads();
        float basev = 0.f;
        #pragma unroll
        for (int w = 0; w < 3; ++w)
            if (w < wv) basev += ws4[w];
        s += basev;
        cum[id * 256 + t] = s;
        if (t == 255) csum[id] = s;
    }
}

// ---------------- scores: S_raw[bc][l][s] = C[l].B[s] (head-independent) ----------------
__global__ __launch_bounds__(256) void score_kernel(
    const unsigned short* __restrict__ xBC, unsigned short* __restrict__ S_raw)
{
    int bc = blockIdx.x;        // 0..63 = b*16+c
    int sq = blockIdx.y;        // 0..3 s-quadrant
    int tid = threadIdx.x;
    int wave = tid >> 6, lane = tid & 63, q = lane >> 4, lm = lane & 15;
    __shared__ __align__(16) unsigned short Ct[256 * 72];
    __shared__ __align__(16) unsigned short Btl[64 * 72];

    #pragma unroll
    for (int i = 0; i < 8; ++i) {
        int idx = tid + 256 * i;
        int r = idx >> 3, ch = idx & 7;
        ushort8 v = *reinterpret_cast<const ushort8*>(
            &xBC[(size_t)(bc * 256 + r) * CONVDIM + DINNER + DSTATE + ch * 8]);
        *reinterpret_cast<ushort8*>(&Ct[r * 72 + ch * 8]) = v;
    }
    #pragma unroll
    for (int i = 0; i < 2; ++i) {
        int idx = tid + 256 * i;
        int r = idx >> 3, ch = idx & 7;
        ushort8 v = *reinterpret_cast<const ushort8*>(
            &xBC[(size_t)(bc * 256 + sq * 64 + r) * CONVDIM + DINNER + ch * 8]);
        *reinterpret_cast<ushort8*>(&Btl[r * 72 + ch * 8]) = v;
    }
    __syncthreads();

    floatx4 acc[4][4] = {};
    #pragma unroll
    for (int ks = 0; ks < 2; ++ks) {
        bf16x8 af[4], bfv[4];
        #pragma unroll
        for (int mt = 0; mt < 4; ++mt)
            af[mt] = *reinterpret_cast<const bf16x8*>(&Ct[(wave * 64 + mt * 16 + lm) * 72 + ks * 32 + q * 8]);
        #pragma unroll
        for (int nt = 0; nt < 4; ++nt)
            bfv[nt] = *reinterpret_cast<const bf16x8*>(&Btl[(nt * 16 + lm) * 72 + ks * 32 + q * 8]);
        #pragma unroll
        for (int mt = 0; mt < 4; ++mt)
            #pragma unroll
            for (int nt = 0; nt < 4; ++nt)
                acc[mt][nt] = __builtin_amdgcn_mfma_f32_16x16x32_bf16(af[mt], bfv[nt], acc[mt][nt], 0, 0, 0);
    }

    #pragma unroll
    for (int mt = 0; mt < 4; ++mt)
        #pragma unroll
        for (int nt = 0; nt < 4; ++nt) {
            int l = wave * 64 + mt * 16 + q * 4;
            int s = sq * 64 + nt * 16 + lm;
            #pragma unroll
            for (int r = 0; r < 4; ++r)
                S_raw[(size_t)(bc * 256 + l + r) * 256 + s] = f2bf(acc[mt][nt][r]);
        }
}

// ---------------- chunk states via MFMA ----------------
__global__ __launch_bounds__(256) void states_kernel(
    const unsigned short* __restrict__ xBC, const float* __restrict__ dtb,
    const float* __restrict__ cum, float* __restrict__ states)
{
    int id = blockIdx.x;
    int h  = id & 31;
    int c  = (id >> 5) & 15;
    int b  = id >> 9;
    int tid = threadIdx.x;
    int wave = tid >> 6, lane = tid & 63, q = lane >> 4, lm = lane & 15;

    __shared__ float wls[256];
    __shared__ __align__(16) unsigned short Xs[64 * 136];
    __shared__ __align__(16) unsigned short Bs[64 * 72];

    const int cumbase = id * 256;
    const int row0 = b * SEQ + c * CHUNKL;
    {
        float cumlast = cum[cumbase + 255];
        wls[tid] = __expf(cumlast - cum[cumbase + tid]) * dtb[(row0 + tid) * NHEADS + h];
    }

    floatx4 acc[2][4] = {};

    for (int sc = 0; sc < 4; ++sc) {
        const int s0 = sc * 64;
        __syncthreads();
        #pragma unroll
        for (int i = 0; i < 4; ++i) {
            int idx = tid + 256 * i;
            int sr = idx >> 4, ch = idx & 15;
            int row = row0 + s0 + sr;
            ushort8 v = *reinterpret_cast<const ushort8*>(
                &xBC[(size_t)row * CONVDIM + h * HEADDIM + ch * 8]);
            float w = wls[s0 + sr];
            ushort8 o;
            #pragma unroll
            for (int j = 0; j < 8; ++j) o[j] = f2bf(bf2f(v[j]) * w);
            *reinterpret_cast<ushort8*>(&Xs[sr * 136 + ch * 8]) = o;
        }
        #pragma unroll
        for (int i = 0; i < 2; ++i) {
            int idx = tid + 256 * i;
            int sr = idx >> 3, ch = idx & 7;
            int row = row0 + s0 + sr;
            ushort8 v = *reinterpret_cast<const ushort8*>(
                &xBC[(size_t)row * CONVDIM + DINNER + ch * 8]);
            *reinterpret_cast<ushort8*>(&Bs[sr * 72 + ch * 8]) = v;
        }
        __syncthreads();
        #pragma unroll
        for (int ks = 0; ks < 2; ++ks) {
            bf16x8 af[2], bfv[4];
            #pragma unroll
            for (int mt = 0; mt < 2; ++mt) {
                int p = wave * 32 + mt * 16 + lm;
                ushort8 tmp;
                #pragma unroll
                for (int j = 0; j < 8; ++j)
                    tmp[j] = Xs[(ks * 32 + q * 8 + j) * 136 + p];
                af[mt] = *reinterpret_cast<bf16x8*>(&tmp);
            }
            #pragma unroll
            for (int nt = 0; nt < 4; ++nt) {
                int n = nt * 16 + lm;
                ushort8 tmp;
                #pragma unroll
                for (int j = 0; j < 8; ++j)
                    tmp[j] = Bs[(ks * 32 + q * 8 + j) * 72 + n];
                bfv[nt] = *reinterpret_cast<bf16x8*>(&tmp);
            }
            #pragma unroll
            for (int mt = 0; mt < 2; ++mt)
                #pragma unroll
                for (int nt = 0; nt < 4; ++nt)
                    acc[mt][nt] = __builtin_amdgcn_mfma_f32_16x16x32_bf16(af[mt], bfv[nt], acc[mt][nt], 0, 0, 0);
        }
    }

    #pragma unroll
    for (int mt = 0; mt < 2; ++mt)
        #pragma unroll
        for (int nt = 0; nt < 4; ++nt)
            #pragma unroll
            for (int r = 0; r < 4; ++r) {
                int p = wave * 32 + mt * 16 + q * 4 + r;
                int n = nt * 16 + lm;
                states[(size_t)id * 8192 + p * 64 + n] = acc[mt][nt][r];
            }
}

// ---------------- inter-chunk recurrence (in-place) ----------------
__global__ __launch_bounds__(256) void inter_kernel(
    float* __restrict__ states, const float* __restrict__ csum)
{
    int idx = blockIdx.x * 256 + threadIdx.x;
    int pn  = idx & 8191;
    int h   = (idx >> 13) & 31;
    int b   = idx >> 18;
    float S = 0.f;
    for (int c = 0; c < 16; ++c) {
        int id = (b * 16 + c) * 32 + h;
        size_t off = (size_t)id * 8192 + pn;
        float st = states[off];
        states[off] = S;
        S = S * __expf(csum[id]) + st;
    }
}

// ---------------- Y via MFMA: Y = P.Xdt + (C*efac).interS^T ----------------
__global__ __launch_bounds__(256) void y_mfma(
    const unsigned short* __restrict__ xBC,
    const unsigned short* __restrict__ S_raw,
    const float* __restrict__ dtb,
    const float* __restrict__ cum,
    const float* __restrict__ inter,
    unsigned short* __restrict__ zx)
{
    int id = blockIdx.x;               // (b*16+c)*32 + h
    int h  = id & 31;
    int bc = id >> 5;
    const int lh = blockIdx.y;         // 0/1 l-half
    int tid = threadIdx.x, wave = tid >> 6, lane = tid & 63, q = lane >> 4, lm = lane & 15;
    int wl = wave >> 1, wp = wave & 1;

    __shared__ float cums[256];
    __shared__ float dts[256];
    __shared__ __align__(16) unsigned short XdtT[128 * 72];   // Xs[64][136] or interS[p][72]
    __shared__ __align__(16) unsigned short PT[128 * 72];     // P[128][72]

    cums[tid] = cum[id * 256 + tid];
    dts[tid]  = dtb[(size_t)(bc * 256 + tid) * NHEADS + h];
    __syncthreads();

    floatx4 acc[4][4] = {};
    const int l0w = lh * 128 + wl * 64;
    const int nst = 2 * lh + 2;

    for (int st = 0; st < nst; ++st) {
        const int s0 = st * 64;
        __syncthreads();
        #pragma unroll
        for (int i = 0; i < 4; ++i) {
            int idx = tid + 256 * i;
            int sr = idx >> 4, ch = idx & 15;
            int srow = bc * 256 + s0 + sr;
            ushort8 v = *reinterpret_cast<const ushort8*>(
                &xBC[(size_t)srow * CONVDIM + h * HEADDIM + ch * 8]);
            float dt = dts[s0 + sr];
            ushort8 o;
            #pragma unroll
            for (int j = 0; j < 8; ++j) o[j] = f2bf(bf2f(v[j]) * dt);
            *reinterpret_cast<ushort8*>(&XdtT[sr * 136 + ch * 8]) = o;
        }
        const int r0 = (s0 > lh * 128) ? 64 : 0;
        const int iters = (128 - r0) >> 5;
        for (int i = 0; i < iters; ++i) {
            int idx = tid + 256 * i;
            int r = r0 + (idx >> 3), ch = idx & 7;
            int l = lh * 128 + r;
            float cl = cums[l];
            ushort8 v = *reinterpret_cast<const ushort8*>(
                &S_raw[(size_t)(bc * 256 + l) * 256 + s0 + ch * 8]);
            ushort8 o;
            #pragma unroll
            for (int j = 0; j < 8; ++j) {
                int s = s0 + ch * 8 + j;
                float val = (s <= l) ? bf2f(v[j]) * __expf(cl - cums[s]) : 0.f;
                o[j] = f2bf(val);
            }
            *reinterpret_cast<ushort8*>(&PT[r * 72 + ch * 8]) = o;
        }
        __syncthreads();
        if (s0 <= l0w) {
            #pragma unroll
            for (int ks = 0; ks < 2; ++ks) {
                bf16x8 af[4], bfv[4];
                #pragma unroll
                for (int mt = 0; mt < 4; ++mt)
                    af[mt] = *reinterpret_cast<const bf16x8*>(
                        &PT[(wl * 64 + mt * 16 + lm) * 72 + ks * 32 + q * 8]);
                #pragma unroll
                for (int nt = 0; nt < 4; ++nt) {
                    int pcol = wp * 64 + nt * 16 + lm;
                    ushort8 tmp;
                    #pragma unroll
                    for (int j = 0; j < 8; ++j)
                        tmp[j] = XdtT[(ks * 32 + q * 8 + j) * 136 + pcol];
                    bfv[nt] = *reinterpret_cast<bf16x8*>(&tmp);
                }
                #pragma unroll
                for (int mt = 0; mt < 4; ++mt)
                    #pragma unroll
                    for (int nt = 0; nt < 4; ++nt)
                        acc[mt][nt] = __builtin_amdgcn_mfma_f32_16x16x32_bf16(af[mt], bfv[nt], acc[mt][nt], 0, 0, 0);
            }
        }
    }

    __syncthreads();
    {
        int p = tid >> 1, n0 = (tid & 1) * 32;
        const float* sp = &inter[(size_t)id * 8192 + p * 64 + n0];
        #pragma unroll
        for (int k2 = 0; k2 < 4; ++k2) {
            float4 a = *reinterpret_cast<const float4*>(sp + k2 * 8);
            float4 b2 = *reinterpret_cast<const float4*>(sp + k2 * 8 + 4);
            ushort8 o;
            o[0] = f2bf(a.x); o[1] = f2bf(a.y); o[2] = f2bf(a.z); o[3] = f2bf(a.w);
            o[4] = f2bf(b2.x); o[5] = f2bf(b2.y); o[6] = f2bf(b2.z); o[7] = f2bf(b2.w);
            *reinterpret_cast<ushort8*>(&XdtT[p * 72 + n0 + k2 * 8]) = o;
        }
        int r = tid >> 1;
        int l = lh * 128 + r;
        float ef = __expf(cums[l]);
        const unsigned short* cp = &xBC[(size_t)(bc * 256 + l) * CONVDIM + DINNER + DSTATE + n0];
        #pragma unroll
        for (int k2 = 0; k2 < 4; ++k2) {
            ushort8 v = *reinterpret_cast<const ushort8*>(cp + k2 * 8);
            ushort8 o;
            #pragma unroll
            for (int j = 0; j < 8; ++j) o[j] = f2bf(bf2f(v[j]) * ef);
            *reinterpret_cast<ushort8*>(&PT[r * 72 + n0 + k2 * 8]) = o;
        }
    }
    __syncthreads();
    #pragma unroll
    for (int ks = 0; ks < 2; ++ks) {
        bf16x8 af[4], bfv[4];
        #pragma unroll
        for (int mt = 0; mt < 4; ++mt)
            af[mt] = *reinterpret_cast<const bf16x8*>(
                &PT[(wl * 64 + mt * 16 + lm) * 72 + ks * 32 + q * 8]);
        #pragma unroll
        for (int nt = 0; nt < 4; ++nt)
            bfv[nt] = *reinterpret_cast<const bf16x8*>(
                &XdtT[(wp * 64 + nt * 16 + lm) * 72 + ks * 32 + q * 8]);
        #pragma unroll
        for (int mt = 0; mt < 4; ++mt)
            #pragma unroll
            for (int nt = 0; nt < 4; ++nt)
                acc[mt][nt] = __builtin_amdgcn_mfma_f32_16x16x32_bf16(af[mt], bfv[nt], acc[mt][nt], 0, 0, 0);
    }

    #pragma unroll
    for (int mt = 0; mt < 4; ++mt)
        #pragma unroll
        for (int nt = 0; nt < 4; ++nt) {
            int l = lh * 128 + wl * 64 + mt * 16 + q * 4;
            int pcol = wp * 64 + nt * 16 + lm;
            #pragma unroll
            for (int r = 0; r < 4; ++r)
                zx[(size_t)(bc * 256 + l + r) * DINPROJ + DINNER + h * HEADDIM + pcol]
                    = f2bf(acc[mt][nt][r]);
        }
}

// ------- fused: y*silu(z) + LayerNorm  AND  out_proj_w fp32->bf16 convert -------
// blocks [0, ROWS): gate_ln (coalesced j-stride access);
// blocks [ROWS, ROWS + 4096): w2 convert (only dep: states dead after y_mfma).
__global__ __launch_bounds__(256) void gate_ln_cvt(
    unsigned short* __restrict__ zx, const float* __restrict__ ln_w,
    const float* __restrict__ ln_b,
    const float* __restrict__ w2, unsigned short* __restrict__ w2_bf)
{
    __shared__ float rs[256], rq[256];
    if (blockIdx.x >= ROWS) {
        cvt8(w2, w2_bf, ((blockIdx.x - ROWS) * 256 + threadIdx.x) * 8);
        return;
    }
    int row = blockIdx.x;
    int t   = threadIdx.x;
    size_t base = (size_t)row * DINPROJ;
    float g[16];
    float sum = 0.f, sumsq = 0.f;
    #pragma unroll
    for (int j = 0; j < 2; ++j) {
        int i = t * 8 + j * 2048;
        ushort8 zv = *reinterpret_cast<const ushort8*>(zx + base + i);
        ushort8 yv = *reinterpret_cast<const ushort8*>(zx + base + DINNER + i);
        #pragma unroll
        for (int k = 0; k < 8; ++k) {
            float z = bf2f(zv[k]);
            float y = bf2f(yv[k]);
            float sig = 1.f / (1.f + __expf(-z));
            float v = y * z * sig;
            g[j * 8 + k] = v;
            sum += v; sumsq += v * v;
        }
    }
    rs[t] = sum; rq[t] = sumsq;
    __syncthreads();
    for (int off = 128; off > 0; off >>= 1) {
        if (t < off) { rs[t] += rs[t + off]; rq[t] += rq[t + off]; }
        __syncthreads();
    }
    float mu   = rs[0] * (1.f / DINNER);
    float var  = rq[0] * (1.f / DINNER) - mu * mu;
    float rstd = rsqrtf(var + 1e-5f);
    #pragma unroll
    for (int j = 0; j < 2; ++j) {
        int i = t * 8 + j * 2048;
        ushort8 o;
        #pragma unroll
        for (int k = 0; k < 8; ++k)
            o[k] = f2bf((g[j * 8 + k] - mu) * rstd * ln_w[i + k] + ln_b[i + k]);
        *reinterpret_cast<ushort8*>(zx + base + DINNER + i) = o;
    }
}

extern "C" void kernel_launch(void* const* d_in, const int* in_sizes, int n_in,
                              void* d_out, int out_size, void* d_ws, size_t ws_size,
                              hipStream_t stream)
{
    const float* u          = (const float*)d_in[0];
    const float* in_proj_w  = (const float*)d_in[1];
    const float* in_proj_b  = (const float*)d_in[2];
    const float* conv_w     = (const float*)d_in[3];
    const float* conv_b     = (const float*)d_in[4];
    const float* dt_bias    = (const float*)d_in[5];
    const float* A_log      = (const float*)d_in[6];
    const float* ln_w       = (const float*)d_in[7];
    const float* ln_b       = (const float*)d_in[8];
    const float* out_proj_w = (const float*)d_in[9];
    const float* out_proj_b = (const float*)d_in[10];
    float* out = (float*)d_out;

    // workspace layout (~238.5 MiB)
    unsigned short* zx  = (unsigned short*)d_ws;              // ROWS*DINPROJ bf16
    unsigned short* xBC = zx + (size_t)ROWS * DINPROJ;        // ROWS*CONVDIM bf16
    float* dtb    = (float*)(xBC + (size_t)ROWS * CONVDIM);   // ROWS*NHEADS f32
    float* cum    = dtb + (size_t)ROWS * NHEADS;              // ROWS*NHEADS f32
    float* csum   = cum + (size_t)ROWS * NHEADS;              // 1024 f32
    float* states = csum + 1024;                              // 1024*8192 f32
    unsigned short* S_raw = (unsigned short*)(states + (size_t)1024 * 8192); // 64*256*256 bf16

    // aliases (no live overlap):
    unsigned short* u_bf  = (unsigned short*)states;          // dead after gemm_in
    unsigned short* w1_bf = xBC;                              // dead after gemm_in
    unsigned short* w2_bf = (unsigned short*)states;          // born after y_mfma

    static bool attr_done = false;
    if (!attr_done) {
        hipFuncSetAttribute(reinterpret_cast<const void*>(&gemm256<1>),
                            hipFuncAttributeMaxDynamicSharedMemorySize, 131072);
        hipFuncSetAttribute(reinterpret_cast<const void*>(&gemm256<0>),
                            hipFuncAttributeMaxDynamicSharedMemorySize, 131072);
        attr_done = true;
    }

    dim3 blk(256);

    // 1) convert u + in_proj_w (one launch)
    const int NBU  = (ROWS * DMODEL) / 2048;      // 8192
    const int NBW1 = (DINPROJ * DMODEL) / 2048;   // 8352
    f32_to_bf16_2<<<dim3(NBU + NBW1), blk, 0, stream>>>(u, u_bf, NBU, in_proj_w, w1_bf);

    // 2) in_proj: M=8192, N=8352, K=2048 (grid 1056, %8==0)
    gemm256<1><<<dim3((ROWS / 256) * ((DINPROJ + 255) / 256)), dim3(512), 131072, stream>>>(
        u_bf, DMODEL, w1_bf, DMODEL, in_proj_b, (void*)zx, DINPROJ, ROWS, DINPROJ, DMODEL);

    // 3) conv+silu AND dt softplus + chunk cumsum (one launch)
    convdt<<<dim3(NCONVB + BATCH * NCHUNK * NHEADS), blk, 0, stream>>>(
        zx, conv_w, conv_b, xBC, dt_bias, A_log, dtb, cum, csum);

    // 4) scores
    score_kernel<<<dim3(BATCH * NCHUNK, 4), blk, 0, stream>>>(xBC, S_raw);

    // 5) chunk states (MFMA)
    states_kernel<<<dim3(BATCH * NCHUNK * NHEADS), blk, 0, stream>>>(xBC, dtb, cum, states);

    // 6) inter-chunk recurrence
    inter_kernel<<<dim3((BATCH * NHEADS * 8192) / 256), blk, 0, stream>>>(states, csum);

    // 7) Y
    y_mfma<<<dim3(BATCH * NCHUNK * NHEADS, 2), blk, 0, stream>>>(xBC, S_raw, dtb, cum, states, zx);

    // 8) gate+LN AND w2 convert (one launch)
    gate_ln_cvt<<<dim3(ROWS + (DMODEL * DINNER) / 2048), blk, 0, stream>>>(
        zx, ln_w, ln_b, out_proj_w, w2_bf);

    // 9) out_proj: M=8192, N=2048, K=4096 (grid 256, %8==0)
    gemm256<0><<<dim3((ROWS / 256) * (DMODEL / 256)), dim3(512), 131072, stream>>>(
        (const unsigned short*)(zx + DINNER), DINPROJ, w2_bf, DINNER, out_proj_b, (void*)out,
        DMODEL, ROWS, DMODEL, DINNER);
}

// Round 7
// 897.964 us; speedup vs baseline: 1.0409x; 1.0104x over previous
//
#include <hip/hip_runtime.h>
#include <math.h>

#define BATCH    2
#define SEQ      4096
#define DMODEL   2048
#define DSTATE   64
#define HEADDIM  128
#define NHEADS   32
#define DINNER   4096
#define CONVDIM  4224
#define DINPROJ  8352
#define NCHUNK   16
#define CHUNKL   256
#define ROWS     (BATCH*SEQ)   // 8192

typedef __attribute__((ext_vector_type(8))) __bf16 bf16x8;
typedef __attribute__((ext_vector_type(4))) float floatx4;
typedef __attribute__((ext_vector_type(8))) unsigned short ushort8;
typedef __attribute__((ext_vector_type(2))) unsigned int uint2v;

__device__ __forceinline__ unsigned short f2bf(float f) {
    union { float f; unsigned int u; } v; v.f = f;
    unsigned int u = v.u;
    unsigned int r = (u + 0x7FFFu + ((u >> 16) & 1u)) >> 16;
    return (unsigned short)r;
}
__device__ __forceinline__ float bf2f(unsigned short s) {
    union { unsigned int u; float f; } v; v.u = ((unsigned int)s) << 16;
    return v.f;
}

__device__ __forceinline__ void gload_lds16(const unsigned short* g, unsigned short* lds) {
    __builtin_amdgcn_global_load_lds(
        (const __attribute__((address_space(1))) unsigned int*)g,
        (__attribute__((address_space(3))) unsigned int*)lds,
        16, 0, 0);
}

// hardware transpose read: lanes of each 16-lane group point at
// vaddr = subtile_base + (lane&15)*8B; HW delivers lane l elem j =
// u16[(l&15) + j*16] of the group's 128B window (4x16 row-major subtile).
__device__ __forceinline__ uint2v tr16(const unsigned short* p) {
    uint2v d;
    asm volatile("ds_read_b64_tr_b16 %0, %1"
                 : "=v"(d)
                 : "v"((const __attribute__((address_space(3))) unsigned short*)p));
    return d;
}
union U8tr { uint2v v2[2]; bf16x8 f; };

__device__ __forceinline__ void cvt8(const float* s, unsigned short* d, int i) {
    float4 a = *reinterpret_cast<const float4*>(s + i);
    float4 b = *reinterpret_cast<const float4*>(s + i + 4);
    ushort8 o;
    o[0] = f2bf(a.x); o[1] = f2bf(a.y); o[2] = f2bf(a.z); o[3] = f2bf(a.w);
    o[4] = f2bf(b.x); o[5] = f2bf(b.y); o[6] = f2bf(b.z); o[7] = f2bf(b.w);
    *reinterpret_cast<ushort8*>(d + i) = o;
}

// ---------------- fused fp32 -> bf16 convert (u + in_proj_w) ----------------
__global__ __launch_bounds__(256) void f32_to_bf16_2(
    const float* __restrict__ s0, unsigned short* __restrict__ d0, int nb0,
    const float* __restrict__ s1, unsigned short* __restrict__ d1)
{
    int b = blockIdx.x;
    if (b < nb0) {
        cvt8(s0, d0, (b * 256 + threadIdx.x) * 8);
    } else {
        cvt8(s1, d1, ((b - nb0) * 256 + threadIdx.x) * 8);
    }
}

// ==================== 256x256 8-phase pipelined GEMM ====================
// (frozen: 36% MfmaUtil, 0 bank conflicts — structural ceiling for this
//  1-block/CU 256^2 shape; see R1/R2/R5 null results)

#define STAGE(G, ldg, grow0, clampmax, k0, off)                                 \
  { int r0_ = (grow0) + sr0; int r1_ = (grow0) + sr1;                           \
    if ((clampmax) >= 0) { if (r0_ > (clampmax)) r0_ = (clampmax);              \
                           if (r1_ > (clampmax)) r1_ = (clampmax); }            \
    unsigned short* d_ = smem + (off) + ldsw;                                   \
    gload_lds16((G) + (size_t)r0_ * (ldg) + (k0) + sc0, d_);                    \
    gload_lds16((G) + (size_t)r1_ * (ldg) + (k0) + sc1, d_ + 4096); }

__device__ __forceinline__ void rd_a(bf16x8 (&dst)[4][2], const unsigned short* base) {
    #pragma unroll
    for (int mt = 0; mt < 4; ++mt)
        #pragma unroll
        for (int ks = 0; ks < 2; ++ks)
            dst[mt][ks] = *reinterpret_cast<const bf16x8*>(base + (mt * 2 + ks) * 512);
}
__device__ __forceinline__ void rd_b(bf16x8 (&dst)[2][2], const unsigned short* base) {
    #pragma unroll
    for (int nt = 0; nt < 2; ++nt)
        #pragma unroll
        for (int ks = 0; ks < 2; ++ks)
            dst[nt][ks] = *reinterpret_cast<const bf16x8*>(base + (nt * 2 + ks) * 512);
}

template<int R0, int C0>
__device__ __forceinline__ void mfma_q(floatx4 (&acc)[8][4],
                                       const bf16x8 (&a)[4][2],
                                       const bf16x8 (&b)[2][2])
{
    #pragma unroll
    for (int mt = 0; mt < 4; ++mt)
        #pragma unroll
        for (int nt = 0; nt < 2; ++nt) {
            acc[R0+mt][C0+nt] = __builtin_amdgcn_mfma_f32_16x16x32_bf16(a[mt][0], b[nt][0], acc[R0+mt][C0+nt], 0, 0, 0);
            acc[R0+mt][C0+nt] = __builtin_amdgcn_mfma_f32_16x16x32_bf16(a[mt][1], b[nt][1], acc[R0+mt][C0+nt], 0, 0, 0);
        }
}

template<int OUT_BF16>
__global__ __launch_bounds__(512, 2) void gemm256(
    const unsigned short* __restrict__ A, int lda,
    const unsigned short* __restrict__ Bt, int ldb,
    const float* __restrict__ bias,
    void* __restrict__ Cp, int ldc,
    int M, int N, int K)
{
    extern __shared__ __align__(16) unsigned short smem[];
    const int tid  = threadIdx.x;
    const int wave = tid >> 6;
    const int lane = tid & 63;
    const int q    = lane >> 4;
    const int lm   = lane & 15;
    const int wm   = wave >> 2;
    const int wn   = wave & 3;
    const int bh   = wn >> 1;
    const int bn2  = wn & 1;

    const int cpx = gridDim.x >> 3;
    const int sid = (blockIdx.x & 7) * cpx + (blockIdx.x >> 3);
    const int nbm = M >> 8;
    const int bm  = sid % nbm;
    const int bn  = sid / nbm;
    const int arow0 = bm * 256;
    const int brow0 = bn * 256;

    int sr0, sc0, sr1, sc1;
    {
        int L = tid << 4;
        int b = L & 1023; b ^= ((b >> 9) & 1) << 5;
        int sub = L >> 10;
        sr0 = ((sub >> 1) << 4) | (b >> 6);
        sc0 = ((sub & 1) << 5) | ((b & 63) >> 1);
        L = 8192 | (tid << 4);
        b = L & 1023; b ^= ((b >> 9) & 1) << 5;
        sub = L >> 10;
        sr1 = ((sub >> 1) << 4) | (b >> 6);
        sc1 = ((sub & 1) << 5) | ((b & 63) >> 1);
    }
    const int ldsw = wave * 512;
    const int lhw = ((((lm << 6) | (q << 4)) ^ ((lm & 8) << 2)) >> 1);
    const int NT  = K >> 6;
    const int NM1 = N - 1;

    STAGE(A,  lda, arow0,       -1,  0,  0);
    STAGE(A,  lda, arow0 + 128, -1,  0,  8192);
    STAGE(Bt, ldb, brow0,       NM1, 0,  16384);
    STAGE(Bt, ldb, brow0 + 128, NM1, 0,  24576);
    STAGE(Bt, ldb, brow0,       NM1, 64, 32768 + 16384);
    STAGE(Bt, ldb, brow0 + 128, NM1, 64, 32768 + 24576);
    STAGE(A,  lda, arow0,       -1,  64, 32768);
    STAGE(A,  lda, arow0 + 128, -1,  64, 32768 + 8192);
    asm volatile("s_waitcnt vmcnt(8)" ::: "memory");
    __builtin_amdgcn_s_barrier();

    const unsigned short* Ab0 = smem + wm * 8192 + lhw;
    const unsigned short* Bb0 = smem + 16384 + bh * 8192 + bn2 * 4096 + lhw;
    const unsigned short* Ab1 = Ab0 + 32768;
    const unsigned short* Bb1 = Bb0 + 32768;

    bf16x8 a_lo[4][2], a_hi[4][2], b_lo[2][2], b_hi[2][2];
    rd_a(a_lo, Ab0);
    rd_b(b_lo, Bb0);

    floatx4 acc[8][4] = {};
    const int NI = NT >> 1;

    for (int i = 0; i < NI; ++i) {
        int tE2 = 2 * i + 2; if (tE2 > NT - 1) tE2 = NT - 1;
        int tO2 = 2 * i + 3; if (tO2 > NT - 1) tO2 = NT - 1;
        const int kE = tE2 << 6, kO = tO2 << 6;

        rd_b(b_hi, Bb0 + 2048);
        __builtin_amdgcn_s_barrier();
        __builtin_amdgcn_s_setprio(1);
        mfma_q<0,0>(acc, a_lo, b_lo);
        __builtin_amdgcn_s_setprio(0);
        __builtin_amdgcn_s_barrier();

        rd_a(a_hi, Ab0 + 4096);
        __builtin_amdgcn_s_barrier();
        __builtin_amdgcn_s_setprio(1);
        mfma_q<0,2>(acc, a_lo, b_hi);
        __builtin_amdgcn_s_setprio(0);
        __builtin_amdgcn_s_barrier();

        STAGE(Bt, ldb, brow0,       NM1, kE, 16384);
        STAGE(Bt, ldb, brow0 + 128, NM1, kE, 24576);
        __builtin_amdgcn_s_barrier();
        __builtin_amdgcn_s_setprio(1);
        mfma_q<4,2>(acc, a_hi, b_hi);
        __builtin_amdgcn_s_setprio(0);
        asm volatile("s_waitcnt vmcnt(4)" ::: "memory");
        __builtin_amdgcn_s_barrier();

        rd_a(a_lo, Ab1);
        rd_b(b_hi, Bb1);
        STAGE(A, lda, arow0,       -1, kE, 0);
        STAGE(A, lda, arow0 + 128, -1, kE, 8192);
        __builtin_amdgcn_s_barrier();
        __builtin_amdgcn_s_setprio(1);
        mfma_q<4,0>(acc, a_hi, b_lo);
        __builtin_amdgcn_s_setprio(0);
        __builtin_amdgcn_s_barrier();

        rd_b(b_lo, Bb1 + 2048);
        __builtin_amdgcn_s_barrier();
        __builtin_amdgcn_s_setprio(1);
        mfma_q<0,0>(acc, a_lo, b_hi);
        __builtin_amdgcn_s_setprio(0);
        __builtin_amdgcn_s_barrier();

        rd_a(a_hi, Ab1 + 4096);
        __builtin_amdgcn_s_barrier();
        __builtin_amdgcn_s_setprio(1);
        mfma_q<0,2>(acc, a_lo, b_lo);
        __builtin_amdgcn_s_setprio(0);
        __builtin_amdgcn_s_barrier();

        STAGE(Bt, ldb, brow0,       NM1, kO, 32768 + 16384);
        STAGE(Bt, ldb, brow0 + 128, NM1, kO, 32768 + 24576);
        __builtin_amdgcn_s_barrier();
        __builtin_amdgcn_s_setprio(1);
        mfma_q<4,2>(acc, a_hi, b_lo);
        __builtin_amdgcn_s_setprio(0);
        asm volatile("s_waitcnt vmcnt(4)" ::: "memory");
        __builtin_amdgcn_s_barrier();

        rd_a(a_lo, Ab0);
        rd_b(b_lo, Bb0);
        STAGE(A, lda, arow0,       -1, kO, 32768);
        STAGE(A, lda, arow0 + 128, -1, kO, 32768 + 8192);
        __builtin_amdgcn_s_barrier();
        __builtin_amdgcn_s_setprio(1);
        mfma_q<4,0>(acc, a_hi, b_hi);
        __builtin_amdgcn_s_setprio(0);
        __builtin_amdgcn_s_barrier();
    }

    asm volatile("s_waitcnt vmcnt(0)" ::: "memory");

    const int row0 = arow0 + wm * 128;
    const int col0 = brow0 + wn * 64;
    #pragma unroll
    for (int mt = 0; mt < 8; ++mt)
        #pragma unroll
        for (int nt = 0; nt < 4; ++nt) {
            int col = col0 + nt * 16 + lm;
            if (col < N) {
                float bv = bias[col];
                #pragma unroll
                for (int r = 0; r < 4; ++r) {
                    int row = row0 + mt * 16 + q * 4 + r;
                    float v = acc[mt][nt][r] + bv;
                    if (OUT_BF16)
                        ((unsigned short*)Cp)[(size_t)row * ldc + col] = f2bf(v);
                    else
                        ((float*)Cp)[(size_t)row * ldc + col] = v;
                }
            }
        }
}

// ------- fused: causal depthwise conv + SiLU  AND  dt softplus + chunk cumsum -------
#define NCONVB (ROWS * (CONVDIM / 8) / 256)   // 16896

__global__ __launch_bounds__(256) void convdt(
    const unsigned short* __restrict__ zx, const float* __restrict__ conv_w,
    const float* __restrict__ conv_b, unsigned short* __restrict__ xBC,
    const float* __restrict__ dt_bias, const float* __restrict__ A_log,
    float* __restrict__ dtb, float* __restrict__ cum, float* __restrict__ csum)
{
    __shared__ float ws4[4];
    if (blockIdx.x < NCONVB) {
        int idx = blockIdx.x * 256 + threadIdx.x;
        int g   = idx % (CONVDIM / 8);
        int row = idx / (CONVDIM / 8);
        int l   = row & (SEQ - 1);
        int ch0 = g * 8;
        const unsigned short* base = zx + (size_t)row * DINPROJ + DINNER + ch0;
        float s[8];
        float4 w4[8];
        #pragma unroll
        for (int c = 0; c < 8; ++c) {
            s[c]  = conv_b[ch0 + c];
            w4[c] = *reinterpret_cast<const float4*>(conv_w + (ch0 + c) * 4);
        }
        #pragma unroll
        for (int j = 0; j < 4; ++j) {
            int lj = l - 3 + j;
            if (lj >= 0) {
                ushort8 v = *reinterpret_cast<const ushort8*>(base + (long)(lj - l) * DINPROJ);
                #pragma unroll
                for (int c = 0; c < 8; ++c) {
                    float wj = (j == 0) ? w4[c].x : (j == 1) ? w4[c].y : (j == 2) ? w4[c].z : w4[c].w;
                    s[c] += wj * bf2f(v[c]);
                }
            }
        }
        ushort8 o;
        #pragma unroll
        for (int c = 0; c < 8; ++c) {
            float sig = 1.f / (1.f + __expf(-s[c]));
            o[c] = f2bf(s[c] * sig);
        }
        *reinterpret_cast<ushort8*>(xBC + (size_t)row * CONVDIM + ch0) = o;
    } else {
        int id = blockIdx.x - NCONVB;
        int h  = id & 31;
        int c  = (id >> 5) & 15;
        int b  = id >> 9;
        int t  = threadIdx.x;
        int row = b * SEQ + c * CHUNKL + t;
        float v = bf2f(zx[(size_t)row * DINPROJ + DINNER + CONVDIM + h]) + dt_bias[h];
        float dtv = (v > 20.f) ? v : log1pf(__expf(v));
        dtb[row * NHEADS + h] = dtv;
        float adt = -__expf(A_log[h]) * dtv;
        int lane = t & 63, wv = t >> 6;
        float s = adt;
        #pragma unroll
        for (int o = 1; o < 64; o <<= 1) {
            float x = __shfl_up(s, o, 64);
            if (lane >= o) s += x;
        }
        if (lane == 63) ws4[wv] = s;
        __syncthreads();
        float basev = 0.f;
        #pragma unroll
        for (int w = 0; w < 3; ++w)
            if (w < wv) basev += ws4[w];
        s += basev;
        cum[id * 256 + t] = s;
        if (t == 255) csum[id] = s;
    }
}

// ---------------- scores: S_raw[bc][l][s] = C[l].B[s] (head-independent) ----------------
__global__ __launch_bounds__(256) void score_kernel(
    const unsigned short* __restrict__ xBC, unsigned short* __restrict__ S_raw)
{
    int bc = blockIdx.x;        // 0..63 = b*16+c
    int sq = blockIdx.y;        // 0..3 s-quadrant
    int tid = threadIdx.x;
    int wave = tid >> 6, lane = tid & 63, q = lane >> 4, lm = lane & 15;
    __shared__ __align__(16) unsigned short Ct[256 * 72];
    __shared__ __align__(16) unsigned short Btl[64 * 72];

    #pragma unroll
    for (int i = 0; i < 8; ++i) {
        int idx = tid + 256 * i;
        int r = idx >> 3, ch = idx & 7;
        ushort8 v = *reinterpret_cast<const ushort8*>(
            &xBC[(size_t)(bc * 256 + r) * CONVDIM + DINNER + DSTATE + ch * 8]);
        *reinterpret_cast<ushort8*>(&Ct[r * 72 + ch * 8]) = v;
    }
    #pragma unroll
    for (int i = 0; i < 2; ++i) {
        int idx = tid + 256 * i;
        int r = idx >> 3, ch = idx & 7;
        ushort8 v = *reinterpret_cast<const ushort8*>(
            &xBC[(size_t)(bc * 256 + sq * 64 + r) * CONVDIM + DINNER + ch * 8]);
        *reinterpret_cast<ushort8*>(&Btl[r * 72 + ch * 8]) = v;
    }
    __syncthreads();

    floatx4 acc[4][4] = {};
    #pragma unroll
    for (int ks = 0; ks < 2; ++ks) {
        bf16x8 af[4], bfv[4];
        #pragma unroll
        for (int mt = 0; mt < 4; ++mt)
            af[mt] = *reinterpret_cast<const bf16x8*>(&Ct[(wave * 64 + mt * 16 + lm) * 72 + ks * 32 + q * 8]);
        #pragma unroll
        for (int nt = 0; nt < 4; ++nt)
            bfv[nt] = *reinterpret_cast<const bf16x8*>(&Btl[(nt * 16 + lm) * 72 + ks * 32 + q * 8]);
        #pragma unroll
        for (int mt = 0; mt < 4; ++mt)
            #pragma unroll
            for (int nt = 0; nt < 4; ++nt)
                acc[mt][nt] = __builtin_amdgcn_mfma_f32_16x16x32_bf16(af[mt], bfv[nt], acc[mt][nt], 0, 0, 0);
    }

    #pragma unroll
    for (int mt = 0; mt < 4; ++mt)
        #pragma unroll
        for (int nt = 0; nt < 4; ++nt) {
            int l = wave * 64 + mt * 16 + q * 4;
            int s = sq * 64 + nt * 16 + lm;
            #pragma unroll
            for (int r = 0; r < 4; ++r)
                S_raw[(size_t)(bc * 256 + l + r) * 256 + s] = f2bf(acc[mt][nt][r]);
        }
}

// ---------------- chunk states via MFMA + tr_read ----------------
// LDS tiles in [si][pi] 4x16-subtile layout (72 u16 padded); fragments via
// ds_read_b64_tr_b16 (2 per fragment) instead of 8 scalar ds_read_u16.
__global__ __launch_bounds__(256) void states_kernel(
    const unsigned short* __restrict__ xBC, const float* __restrict__ dtb,
    const float* __restrict__ cum, float* __restrict__ states)
{
    int id = blockIdx.x;
    int h  = id & 31;
    int c  = (id >> 5) & 15;
    int b  = id >> 9;
    int tid = threadIdx.x;
    int wave = tid >> 6, lane = tid & 63, q = lane >> 4, lm = lane & 15;

    __shared__ float wls[256];
    __shared__ __align__(16) unsigned short Xs[16 * 8 * 72];   // [si][pi][4][16]+pad
    __shared__ __align__(16) unsigned short Bs[16 * 4 * 72];

    const int cumbase = id * 256;
    const int row0 = b * SEQ + c * CHUNKL;
    {
        float cumlast = cum[cumbase + 255];
        wls[tid] = __expf(cumlast - cum[cumbase + tid]) * dtb[(row0 + tid) * NHEADS + h];
    }

    floatx4 acc[2][4] = {};

    for (int sc = 0; sc < 4; ++sc) {
        const int s0 = sc * 64;
        __syncthreads();
        // stage Xw into subtiles: (s=sr, p=ch*8+e) -> [sr>>2][ch>>1] row sr&3 col (ch&1)*8+e
        #pragma unroll
        for (int i = 0; i < 4; ++i) {
            int idx = tid + 256 * i;
            int sr = idx >> 4, ch = idx & 15;
            int row = row0 + s0 + sr;
            ushort8 v = *reinterpret_cast<const ushort8*>(
                &xBC[(size_t)row * CONVDIM + h * HEADDIM + ch * 8]);
            float w = wls[s0 + sr];
            ushort8 o;
            #pragma unroll
            for (int j = 0; j < 8; ++j) o[j] = f2bf(bf2f(v[j]) * w);
            int a = ((sr >> 2) * 8 + (ch >> 1)) * 72 + (sr & 3) * 16 + (ch & 1) * 8;
            *reinterpret_cast<ushort8*>(&Xs[a]) = o;
        }
        // stage B into subtiles (NP=4)
        #pragma unroll
        for (int i = 0; i < 2; ++i) {
            int idx = tid + 256 * i;
            int sr = idx >> 3, ch = idx & 7;
            int row = row0 + s0 + sr;
            ushort8 v = *reinterpret_cast<const ushort8*>(
                &xBC[(size_t)row * CONVDIM + DINNER + ch * 8]);
            int a = ((sr >> 2) * 4 + (ch >> 1)) * 72 + (sr & 3) * 16 + (ch & 1) * 8;
            *reinterpret_cast<ushort8*>(&Bs[a]) = v;
        }
        __syncthreads();
        #pragma unroll
        for (int ks = 0; ks < 2; ++ks) {
            bf16x8 af[2], bfv[4];
            #pragma unroll
            for (int mt = 0; mt < 2; ++mt) {
                const unsigned short* vp = Xs + ((ks * 8 + 2 * q) * 8 + (wave * 2 + mt)) * 72 + lm * 4;
                U8tr u; u.v2[0] = tr16(vp); u.v2[1] = tr16(vp + 576);
                af[mt] = u.f;
            }
            #pragma unroll
            for (int nt = 0; nt < 4; ++nt) {
                const unsigned short* vp = Bs + ((ks * 8 + 2 * q) * 4 + nt) * 72 + lm * 4;
                U8tr u; u.v2[0] = tr16(vp); u.v2[1] = tr16(vp + 288);
                bfv[nt] = u.f;
            }
            asm volatile("s_waitcnt lgkmcnt(0)" ::: "memory");
            __builtin_amdgcn_sched_barrier(0);
            #pragma unroll
            for (int mt = 0; mt < 2; ++mt)
                #pragma unroll
                for (int nt = 0; nt < 4; ++nt)
                    acc[mt][nt] = __builtin_amdgcn_mfma_f32_16x16x32_bf16(af[mt], bfv[nt], acc[mt][nt], 0, 0, 0);
        }
    }

    #pragma unroll
    for (int mt = 0; mt < 2; ++mt)
        #pragma unroll
        for (int nt = 0; nt < 4; ++nt)
            #pragma unroll
            for (int r = 0; r < 4; ++r) {
                int p = wave * 32 + mt * 16 + q * 4 + r;
                int n = nt * 16 + lm;
                states[(size_t)id * 8192 + p * 64 + n] = acc[mt][nt][r];
            }
}

// ---------------- inter-chunk recurrence (in-place) ----------------
__global__ __launch_bounds__(256) void inter_kernel(
    float* __restrict__ states, const float* __restrict__ csum)
{
    int idx = blockIdx.x * 256 + threadIdx.x;
    int pn  = idx & 8191;
    int h   = (idx >> 13) & 31;
    int b   = idx >> 18;
    float S = 0.f;
    for (int c = 0; c < 16; ++c) {
        int id = (b * 16 + c) * 32 + h;
        size_t off = (size_t)id * 8192 + pn;
        float st = states[off];
        states[off] = S;
        S = S * __expf(csum[id]) + st;
    }
}

// ---------------- Y via MFMA: Y = P.Xdt + (C*efac).interS^T ----------------
// v4: Xdt tile in [si][pi] subtile layout; B-fragments via tr_read
// (2 x ds_read_b64_tr_b16) instead of 8 scalar ds_read_u16 each.
__global__ __launch_bounds__(256) void y_mfma(
    const unsigned short* __restrict__ xBC,
    const unsigned short* __restrict__ S_raw,
    const float* __restrict__ dtb,
    const float* __restrict__ cum,
    const float* __restrict__ inter,
    unsigned short* __restrict__ zx)
{
    int id = blockIdx.x;               // (b*16+c)*32 + h
    int h  = id & 31;
    int bc = id >> 5;
    const int lh = blockIdx.y;         // 0/1 l-half
    int tid = threadIdx.x, wave = tid >> 6, lane = tid & 63, q = lane >> 4, lm = lane & 15;
    int wl = wave >> 1, wp = wave & 1;

    __shared__ float cums[256];
    __shared__ float dts[256];
    __shared__ __align__(16) unsigned short XdtT[128 * 72];   // subtiled Xdt or interS[p][72]
    __shared__ __align__(16) unsigned short PT[128 * 72];     // P[128][72]

    cums[tid] = cum[id * 256 + tid];
    dts[tid]  = dtb[(size_t)(bc * 256 + tid) * NHEADS + h];
    __syncthreads();

    floatx4 acc[4][4] = {};
    const int l0w = lh * 128 + wl * 64;
    const int nst = 2 * lh + 2;

    for (int st = 0; st < nst; ++st) {
        const int s0 = st * 64;
        __syncthreads();
        // --- stage Xdt into [si][pi] subtiles (NP=8, 16 si x 8 pi) ---
        #pragma unroll
        for (int i = 0; i < 4; ++i) {
            int idx = tid + 256 * i;
            int sr = idx >> 4, ch = idx & 15;
            int srow = bc * 256 + s0 + sr;
            ushort8 v = *reinterpret_cast<const ushort8*>(
                &xBC[(size_t)srow * CONVDIM + h * HEADDIM + ch * 8]);
            float dt = dts[s0 + sr];
            ushort8 o;
            #pragma unroll
            for (int j = 0; j < 8; ++j) o[j] = f2bf(bf2f(v[j]) * dt);
            int a = ((sr >> 2) * 8 + (ch >> 1)) * 72 + (sr & 3) * 16 + (ch & 1) * 8;
            *reinterpret_cast<ushort8*>(&XdtT[a]) = o;
        }
        // --- P stage: rows r in [r0,128) of this half (decay+mask, bf16) ---
        const int r0 = (s0 > lh * 128) ? 64 : 0;
        const int iters = (128 - r0) >> 5;
        for (int i = 0; i < iters; ++i) {
            int idx = tid + 256 * i;
            int r = r0 + (idx >> 3), ch = idx & 7;
            int l = lh * 128 + r;
            float cl = cums[l];
            ushort8 v = *reinterpret_cast<const ushort8*>(
                &S_raw[(size_t)(bc * 256 + l) * 256 + s0 + ch * 8]);
            ushort8 o;
            #pragma unroll
            for (int j = 0; j < 8; ++j) {
                int s = s0 + ch * 8 + j;
                float val = (s <= l) ? bf2f(v[j]) * __expf(cl - cums[s]) : 0.f;
                o[j] = f2bf(val);
            }
            *reinterpret_cast<ushort8*>(&PT[r * 72 + ch * 8]) = o;
        }
        __syncthreads();
        // --- MFMA (waves with l >= s participate) ---
        if (s0 <= l0w) {
            #pragma unroll
            for (int ks = 0; ks < 2; ++ks) {
                bf16x8 af[4], bfv[4];
                #pragma unroll
                for (int mt = 0; mt < 4; ++mt)
                    af[mt] = *reinterpret_cast<const bf16x8*>(
                        &PT[(wl * 64 + mt * 16 + lm) * 72 + ks * 32 + q * 8]);
                #pragma unroll
                for (int nt = 0; nt < 4; ++nt) {
                    const unsigned short* vp = XdtT + ((ks * 8 + 2 * q) * 8 + (wp * 4 + nt)) * 72 + lm * 4;
                    U8tr u; u.v2[0] = tr16(vp); u.v2[1] = tr16(vp + 576);
                    bfv[nt] = u.f;
                }
                asm volatile("s_waitcnt lgkmcnt(0)" ::: "memory");
                __builtin_amdgcn_sched_barrier(0);
                #pragma unroll
                for (int mt = 0; mt < 4; ++mt)
                    #pragma unroll
                    for (int nt = 0; nt < 4; ++nt)
                        acc[mt][nt] = __builtin_amdgcn_mfma_f32_16x16x32_bf16(af[mt], bfv[nt], acc[mt][nt], 0, 0, 0);
            }
        }
    }

    // --- virtual tile: Y_off = (C*efac) . interS^T (row-major layouts, vector reads) ---
    __syncthreads();
    {
        int p = tid >> 1, n0 = (tid & 1) * 32;
        const float* sp = &inter[(size_t)id * 8192 + p * 64 + n0];
        #pragma unroll
        for (int k2 = 0; k2 < 4; ++k2) {
            float4 a = *reinterpret_cast<const float4*>(sp + k2 * 8);
            float4 b2 = *reinterpret_cast<const float4*>(sp + k2 * 8 + 4);
            ushort8 o;
            o[0] = f2bf(a.x); o[1] = f2bf(a.y); o[2] = f2bf(a.z); o[3] = f2bf(a.w);
            o[4] = f2bf(b2.x); o[5] = f2bf(b2.y); o[6] = f2bf(b2.z); o[7] = f2bf(b2.w);
            *reinterpret_cast<ushort8*>(&XdtT[p * 72 + n0 + k2 * 8]) = o;
        }
        int r = tid >> 1;
        int l = lh * 128 + r;
        float ef = __expf(cums[l]);
        const unsigned short* cp = &xBC[(size_t)(bc * 256 + l) * CONVDIM + DINNER + DSTATE + n0];
        #pragma unroll
        for (int k2 = 0; k2 < 4; ++k2) {
            ushort8 v = *reinterpret_cast<const ushort8*>(cp + k2 * 8);
            ushort8 o;
            #pragma unroll
            for (int j = 0; j < 8; ++j) o[j] = f2bf(bf2f(v[j]) * ef);
            *reinterpret_cast<ushort8*>(&PT[r * 72 + n0 + k2 * 8]) = o;
        }
    }
    __syncthreads();
    #pragma unroll
    for (int ks = 0; ks < 2; ++ks) {
        bf16x8 af[4], bfv[4];
        #pragma unroll
        for (int mt = 0; mt < 4; ++mt)
            af[mt] = *reinterpret_cast<const bf16x8*>(
                &PT[(wl * 64 + mt * 16 + lm) * 72 + ks * 32 + q * 8]);
        #pragma unroll
        for (int nt = 0; nt < 4; ++nt)
            bfv[nt] = *reinterpret_cast<const bf16x8*>(
                &XdtT[(wp * 64 + nt * 16 + lm) * 72 + ks * 32 + q * 8]);
        #pragma unroll
        for (int mt = 0; mt < 4; ++mt)
            #pragma unroll
            for (int nt = 0; nt < 4; ++nt)
                acc[mt][nt] = __builtin_amdgcn_mfma_f32_16x16x32_bf16(af[mt], bfv[nt], acc[mt][nt], 0, 0, 0);
    }

    #pragma unroll
    for (int mt = 0; mt < 4; ++mt)
        #pragma unroll
        for (int nt = 0; nt < 4; ++nt) {
            int l = lh * 128 + wl * 64 + mt * 16 + q * 4;
            int pcol = wp * 64 + nt * 16 + lm;
            #pragma unroll
            for (int r = 0; r < 4; ++r)
                zx[(size_t)(bc * 256 + l + r) * DINPROJ + DINNER + h * HEADDIM + pcol]
                    = f2bf(acc[mt][nt][r]);
        }
}

// ------- fused: y*silu(z) + LayerNorm  AND  out_proj_w fp32->bf16 convert -------
__global__ __launch_bounds__(256) void gate_ln_cvt(
    unsigned short* __restrict__ zx, const float* __restrict__ ln_w,
    const float* __restrict__ ln_b,
    const float* __restrict__ w2, unsigned short* __restrict__ w2_bf)
{
    __shared__ float rs[256], rq[256];
    if (blockIdx.x >= ROWS) {
        cvt8(w2, w2_bf, ((blockIdx.x - ROWS) * 256 + threadIdx.x) * 8);
        return;
    }
    int row = blockIdx.x;
    int t   = threadIdx.x;
    size_t base = (size_t)row * DINPROJ;
    float g[16];
    float sum = 0.f, sumsq = 0.f;
    #pragma unroll
    for (int j = 0; j < 2; ++j) {
        int i = t * 8 + j * 2048;
        ushort8 zv = *reinterpret_cast<const ushort8*>(zx + base + i);
        ushort8 yv = *reinterpret_cast<const ushort8*>(zx + base + DINNER + i);
        #pragma unroll
        for (int k = 0; k < 8; ++k) {
            float z = bf2f(zv[k]);
            float y = bf2f(yv[k]);
            float sig = 1.f / (1.f + __expf(-z));
            float v = y * z * sig;
            g[j * 8 + k] = v;
            sum += v; sumsq += v * v;
        }
    }
    rs[t] = sum; rq[t] = sumsq;
    __syncthreads();
    for (int off = 128; off > 0; off >>= 1) {
        if (t < off) { rs[t] += rs[t + off]; rq[t] += rq[t + off]; }
        __syncthreads();
    }
    float mu   = rs[0] * (1.f / DINNER);
    float var  = rq[0] * (1.f / DINNER) - mu * mu;
    float rstd = rsqrtf(var + 1e-5f);
    #pragma unroll
    for (int j = 0; j < 2; ++j) {
        int i = t * 8 + j * 2048;
        ushort8 o;
        #pragma unroll
        for (int k = 0; k < 8; ++k)
            o[k] = f2bf((g[j * 8 + k] - mu) * rstd * ln_w[i + k] + ln_b[i + k]);
        *reinterpret_cast<ushort8*>(zx + base + DINNER + i) = o;
    }
}

extern "C" void kernel_launch(void* const* d_in, const int* in_sizes, int n_in,
                              void* d_out, int out_size, void* d_ws, size_t ws_size,
                              hipStream_t stream)
{
    const float* u          = (const float*)d_in[0];
    const float* in_proj_w  = (const float*)d_in[1];
    const float* in_proj_b  = (const float*)d_in[2];
    const float* conv_w     = (const float*)d_in[3];
    const float* conv_b     = (const float*)d_in[4];
    const float* dt_bias    = (const float*)d_in[5];
    const float* A_log      = (const float*)d_in[6];
    const float* ln_w       = (const float*)d_in[7];
    const float* ln_b       = (const float*)d_in[8];
    const float* out_proj_w = (const float*)d_in[9];
    const float* out_proj_b = (const float*)d_in[10];
    float* out = (float*)d_out;

    // workspace layout (~238.5 MiB)
    unsigned short* zx  = (unsigned short*)d_ws;              // ROWS*DINPROJ bf16
    unsigned short* xBC = zx + (size_t)ROWS * DINPROJ;        // ROWS*CONVDIM bf16
    float* dtb    = (float*)(xBC + (size_t)ROWS * CONVDIM);   // ROWS*NHEADS f32
    float* cum    = dtb + (size_t)ROWS * NHEADS;              // ROWS*NHEADS f32
    float* csum   = cum + (size_t)ROWS * NHEADS;              // 1024 f32
    float* states = csum + 1024;                              // 1024*8192 f32
    unsigned short* S_raw = (unsigned short*)(states + (size_t)1024 * 8192); // 64*256*256 bf16

    // aliases (no live overlap):
    unsigned short* u_bf  = (unsigned short*)states;          // dead after gemm_in
    unsigned short* w1_bf = xBC;                              // dead after gemm_in
    unsigned short* w2_bf = (unsigned short*)states;          // born after y_mfma

    static bool attr_done = false;
    if (!attr_done) {
        hipFuncSetAttribute(reinterpret_cast<const void*>(&gemm256<1>),
                            hipFuncAttributeMaxDynamicSharedMemorySize, 131072);
        hipFuncSetAttribute(reinterpret_cast<const void*>(&gemm256<0>),
                            hipFuncAttributeMaxDynamicSharedMemorySize, 131072);
        attr_done = true;
    }

    dim3 blk(256);

    const int NBU  = (ROWS * DMODEL) / 2048;      // 8192
    const int NBW1 = (DINPROJ * DMODEL) / 2048;   // 8352
    f32_to_bf16_2<<<dim3(NBU + NBW1), blk, 0, stream>>>(u, u_bf, NBU, in_proj_w, w1_bf);

    gemm256<1><<<dim3((ROWS / 256) * ((DINPROJ + 255) / 256)), dim3(512), 131072, stream>>>(
        u_bf, DMODEL, w1_bf, DMODEL, in_proj_b, (void*)zx, DINPROJ, ROWS, DINPROJ, DMODEL);

    convdt<<<dim3(NCONVB + BATCH * NCHUNK * NHEADS), blk, 0, stream>>>(
        zx, conv_w, conv_b, xBC, dt_bias, A_log, dtb, cum, csum);

    score_kernel<<<dim3(BATCH * NCHUNK, 4), blk, 0, stream>>>(xBC, S_raw);

    states_kernel<<<dim3(BATCH * NCHUNK * NHEADS), blk, 0, stream>>>(xBC, dtb, cum, states);

    inter_kernel<<<dim3((BATCH * NHEADS * 8192) / 256), blk, 0, stream>>>(states, csum);

    y_mfma<<<dim3(BATCH * NCHUNK * NHEADS, 2), blk, 0, stream>>>(xBC, S_raw, dtb, cum, states, zx);

    gate_ln_cvt<<<dim3(ROWS + (DMODEL * DINNER) / 2048), blk, 0, stream>>>(
        zx, ln_w, ln_b, out_proj_w, w2_bf);

    gemm256<0><<<dim3((ROWS / 256) * (DMODEL / 256)), dim3(512), 131072, stream>>>(
        (const unsigned short*)(zx + DINNER), DINPROJ, w2_bf, DINNER, out_proj_b, (void*)out,
        DMODEL, ROWS, DMODEL, DINNER);
}

// Round 8
// 889.093 us; speedup vs baseline: 1.0513x; 1.0100x over previous
//
#include <hip/hip_runtime.h>
#include <math.h>

#define BATCH    2
#define SEQ      4096
#define DMODEL   2048
#define DSTATE   64
#define HEADDIM  128
#define NHEADS   32
#define DINNER   4096
#define CONVDIM  4224
#define DINPROJ  8352
#define NCHUNK   16
#define CHUNKL   256
#define ROWS     (BATCH*SEQ)   // 8192

typedef __attribute__((ext_vector_type(8))) __bf16 bf16x8;
typedef __attribute__((ext_vector_type(4))) float floatx4;
typedef __attribute__((ext_vector_type(8))) unsigned short ushort8;
typedef __attribute__((ext_vector_type(2))) unsigned int uint2v;

__device__ __forceinline__ unsigned short f2bf(float f) {
    union { float f; unsigned int u; } v; v.f = f;
    unsigned int u = v.u;
    unsigned int r = (u + 0x7FFFu + ((u >> 16) & 1u)) >> 16;
    return (unsigned short)r;
}
__device__ __forceinline__ float bf2f(unsigned short s) {
    union { unsigned int u; float f; } v; v.u = ((unsigned int)s) << 16;
    return v.f;
}

__device__ __forceinline__ void gload_lds16(const unsigned short* g, unsigned short* lds) {
    __builtin_amdgcn_global_load_lds(
        (const __attribute__((address_space(1))) unsigned int*)g,
        (__attribute__((address_space(3))) unsigned int*)lds,
        16, 0, 0);
}

// hardware transpose read (see round-7 notes; verified by refcheck)
__device__ __forceinline__ uint2v tr16(const unsigned short* p) {
    uint2v d;
    asm volatile("ds_read_b64_tr_b16 %0, %1"
                 : "=v"(d)
                 : "v"((const __attribute__((address_space(3))) unsigned short*)p));
    return d;
}
union U8tr { uint2v v2[2]; bf16x8 f; };

__device__ __forceinline__ void cvt8(const float* s, unsigned short* d, int i) {
    float4 a = *reinterpret_cast<const float4*>(s + i);
    float4 b = *reinterpret_cast<const float4*>(s + i + 4);
    ushort8 o;
    o[0] = f2bf(a.x); o[1] = f2bf(a.y); o[2] = f2bf(a.z); o[3] = f2bf(a.w);
    o[4] = f2bf(b.x); o[5] = f2bf(b.y); o[6] = f2bf(b.z); o[7] = f2bf(b.w);
    *reinterpret_cast<ushort8*>(d + i) = o;
}

// ---------------- fused fp32 -> bf16 convert (u + in_proj_w) ----------------
__global__ __launch_bounds__(256) void f32_to_bf16_2(
    const float* __restrict__ s0, unsigned short* __restrict__ d0, int nb0,
    const float* __restrict__ s1, unsigned short* __restrict__ d1)
{
    int b = blockIdx.x;
    if (b < nb0) {
        cvt8(s0, d0, (b * 256 + threadIdx.x) * 8);
    } else {
        cvt8(s1, d1, ((b - nb0) * 256 + threadIdx.x) * 8);
    }
}

// ==================== 256x256 8-phase pipelined GEMM v4 ====================
// v4 (m201-parity pass): 1 half-tile stage per phase at earliest barrier-safe
// slot; counted vmcnt(6) once per K-tile (3 halves in flight); grouped 2D
// rasterization (GROUP_M=8) under the XCD swizzle for A/B-panel L2 reuse;
// wave-uniform dead-column MFMA skip (in_proj N-edge blocks).

#define STAGE(G, ldg, grow0, clampmax, k0, off)                                 \
  { int r0_ = (grow0) + sr0; int r1_ = (grow0) + sr1;                           \
    if ((clampmax) >= 0) { if (r0_ > (clampmax)) r0_ = (clampmax);              \
                           if (r1_ > (clampmax)) r1_ = (clampmax); }            \
    unsigned short* d_ = smem + (off) + ldsw;                                   \
    gload_lds16((G) + (size_t)r0_ * (ldg) + (k0) + sc0, d_);                    \
    gload_lds16((G) + (size_t)r1_ * (ldg) + (k0) + sc1, d_ + 4096); }

__device__ __forceinline__ void rd_a(bf16x8 (&dst)[4][2], const unsigned short* base) {
    #pragma unroll
    for (int mt = 0; mt < 4; ++mt)
        #pragma unroll
        for (int ks = 0; ks < 2; ++ks)
            dst[mt][ks] = *reinterpret_cast<const bf16x8*>(base + (mt * 2 + ks) * 512);
}
__device__ __forceinline__ void rd_b(bf16x8 (&dst)[2][2], const unsigned short* base) {
    #pragma unroll
    for (int nt = 0; nt < 2; ++nt)
        #pragma unroll
        for (int ks = 0; ks < 2; ++ks)
            dst[nt][ks] = *reinterpret_cast<const bf16x8*>(base + (nt * 2 + ks) * 512);
}

template<int R0, int C0>
__device__ __forceinline__ void mfma_q(floatx4 (&acc)[8][4],
                                       const bf16x8 (&a)[4][2],
                                       const bf16x8 (&b)[2][2])
{
    #pragma unroll
    for (int mt = 0; mt < 4; ++mt)
        #pragma unroll
        for (int nt = 0; nt < 2; ++nt) {
            acc[R0+mt][C0+nt] = __builtin_amdgcn_mfma_f32_16x16x32_bf16(a[mt][0], b[nt][0], acc[R0+mt][C0+nt], 0, 0, 0);
            acc[R0+mt][C0+nt] = __builtin_amdgcn_mfma_f32_16x16x32_bf16(a[mt][1], b[nt][1], acc[R0+mt][C0+nt], 0, 0, 0);
        }
}

#define MQ(R0, C0, A_, B_)                          \
    __builtin_amdgcn_s_setprio(1);                  \
    if (alive) mfma_q<R0, C0>(acc, A_, B_);         \
    __builtin_amdgcn_s_setprio(0);

template<int OUT_BF16>
__global__ __launch_bounds__(512, 2) void gemm256(
    const unsigned short* __restrict__ A, int lda,
    const unsigned short* __restrict__ Bt, int ldb,
    const float* __restrict__ bias,
    void* __restrict__ Cp, int ldc,
    int M, int N, int K)
{
    extern __shared__ __align__(16) unsigned short smem[];
    const int tid  = threadIdx.x;
    const int wave = tid >> 6;
    const int lane = tid & 63;
    const int q    = lane >> 4;
    const int lm   = lane & 15;
    const int wm   = wave >> 2;
    const int wn   = wave & 3;
    const int bh   = wn >> 1;
    const int bn2  = wn & 1;

    // XCD swizzle, then grouped 2D rasterization (GROUP_M=8 bm-rows per group)
    const int cpx = gridDim.x >> 3;
    const int sid = (blockIdx.x & 7) * cpx + (blockIdx.x >> 3);
    const int nbm = M >> 8;
    const int nbn = gridDim.x / nbm;
    int bm, bn;
    {
        const int GM = 8;
        int nig = GM * nbn;
        int grp = sid / nig;
        int first = grp * GM;
        int gsz = nbm - first; if (gsz > GM) gsz = GM;
        bm = first + (sid % nig) % gsz;
        bn = (sid % nig) / gsz;
    }
    const int arow0 = bm * 256;
    const int brow0 = bn * 256;
    const bool alive = (brow0 + wn * 64) < N;   // wave-uniform dead-column skip

    int sr0, sc0, sr1, sc1;
    {
        int L = tid << 4;
        int b = L & 1023; b ^= ((b >> 9) & 1) << 5;
        int sub = L >> 10;
        sr0 = ((sub >> 1) << 4) | (b >> 6);
        sc0 = ((sub & 1) << 5) | ((b & 63) >> 1);
        L = 8192 | (tid << 4);
        b = L & 1023; b ^= ((b >> 9) & 1) << 5;
        sub = L >> 10;
        sr1 = ((sub >> 1) << 4) | (b >> 6);
        sc1 = ((sub & 1) << 5) | ((b & 63) >> 1);
    }
    const int ldsw = wave * 512;
    const int lhw = ((((lm << 6) | (q << 4)) ^ ((lm & 8) << 2)) >> 1);
    const int NT  = K >> 6;        // even for both call sites
    const int NM1 = N - 1;

    // ---- prologue: tile0 -> buf0, tile1 -> buf1 ----
    STAGE(A,  lda, arow0,       -1,  0,  0);
    STAGE(A,  lda, arow0 + 128, -1,  0,  8192);
    STAGE(Bt, ldb, brow0,       NM1, 0,  16384);
    STAGE(Bt, ldb, brow0 + 128, NM1, 0,  24576);
    STAGE(Bt, ldb, brow0,       NM1, 64, 32768 + 16384);
    STAGE(Bt, ldb, brow0 + 128, NM1, 64, 32768 + 24576);
    STAGE(A,  lda, arow0,       -1,  64, 32768);
    STAGE(A,  lda, arow0 + 128, -1,  64, 32768 + 8192);
    asm volatile("s_waitcnt vmcnt(8)" ::: "memory");
    __builtin_amdgcn_s_barrier();

    const unsigned short* Ab0 = smem + wm * 8192 + lhw;
    const unsigned short* Bb0 = smem + 16384 + bh * 8192 + bn2 * 4096 + lhw;
    const unsigned short* Ab1 = Ab0 + 32768;
    const unsigned short* Bb1 = Bb0 + 32768;

    bf16x8 a_lo[4][2], a_hi[4][2], b_lo[2][2], b_hi[2][2];
    rd_a(a_lo, Ab0);
    rd_b(b_lo, Bb0);

    floatx4 acc[8][4] = {};
    const int NI = NT >> 1;

    for (int i = 0; i < NI; ++i) {
        int tE2 = 2 * i + 2; if (tE2 > NT - 1) tE2 = NT - 1;
        int tO2 = 2 * i + 3; if (tO2 > NT - 1) tO2 = NT - 1;
        const int kE = tE2 << 6, kO = tO2 << 6;

        // P1: read qb1(E); MFMA Q00(E)
        rd_b(b_hi, Bb0 + 2048);
        __builtin_amdgcn_s_barrier();
        MQ(0, 0, a_lo, b_lo);
        __builtin_amdgcn_s_barrier();

        // P2: read qa1(E); stage B-h0(E+2); MFMA Q01(E)
        rd_a(a_hi, Ab0 + 4096);
        STAGE(Bt, ldb, brow0, NM1, kE, 16384);
        __builtin_amdgcn_s_barrier();
        MQ(0, 2, a_lo, b_hi);
        __builtin_amdgcn_s_barrier();

        // P3: stage B-h1(E+2) + A-h0(E+2); MFMA Q11(E); drain tile O (vmcnt 6)
        STAGE(Bt, ldb, brow0 + 128, NM1, kE, 24576);
        STAGE(A,  lda, arow0,       -1,  kE, 0);
        __builtin_amdgcn_s_barrier();
        MQ(4, 2, a_hi, b_hi);
        asm volatile("s_waitcnt vmcnt(6)" ::: "memory");
        __builtin_amdgcn_s_barrier();

        // P4: read qa0(O)+qb0(O); stage A-h1(E+2); MFMA Q10(E)
        rd_a(a_lo, Ab1);
        rd_b(b_hi, Bb1);
        STAGE(A, lda, arow0 + 128, -1, kE, 8192);
        __builtin_amdgcn_s_barrier();
        MQ(4, 0, a_hi, b_lo);
        __builtin_amdgcn_s_barrier();

        // P5: read qb1(O); MFMA Q00(O)
        rd_b(b_lo, Bb1 + 2048);
        __builtin_amdgcn_s_barrier();
        MQ(0, 0, a_lo, b_hi);
        __builtin_amdgcn_s_barrier();

        // P6: read qa1(O); stage B-h0(O+2); MFMA Q01(O)
        rd_a(a_hi, Ab1 + 4096);
        STAGE(Bt, ldb, brow0, NM1, kO, 32768 + 16384);
        __builtin_amdgcn_s_barrier();
        MQ(0, 2, a_lo, b_lo);
        __builtin_amdgcn_s_barrier();

        // P7: stage B-h1(O+2) + A-h0(O+2); MFMA Q11(O); drain tile E+2 (vmcnt 6)
        STAGE(Bt, ldb, brow0 + 128, NM1, kO, 32768 + 24576);
        STAGE(A,  lda, arow0,       -1,  kO, 32768);
        __builtin_amdgcn_s_barrier();
        MQ(4, 2, a_hi, b_lo);
        asm volatile("s_waitcnt vmcnt(6)" ::: "memory");
        __builtin_amdgcn_s_barrier();

        // P8: read qa0(E')+qb0(E'); stage A-h1(O+2); MFMA Q10(O)
        rd_a(a_lo, Ab0);
        rd_b(b_lo, Bb0);
        STAGE(A, lda, arow0 + 128, -1, kO, 32768 + 8192);
        __builtin_amdgcn_s_barrier();
        MQ(4, 0, a_hi, b_hi);
        __builtin_amdgcn_s_barrier();
    }

    asm volatile("s_waitcnt vmcnt(0)" ::: "memory");

    const int row0 = arow0 + wm * 128;
    const int col0 = brow0 + wn * 64;
    #pragma unroll
    for (int mt = 0; mt < 8; ++mt)
        #pragma unroll
        for (int nt = 0; nt < 4; ++nt) {
            int col = col0 + nt * 16 + lm;
            if (col < N) {
                float bv = bias[col];
                #pragma unroll
                for (int r = 0; r < 4; ++r) {
                    int row = row0 + mt * 16 + q * 4 + r;
                    float v = acc[mt][nt][r] + bv;
                    if (OUT_BF16)
                        ((unsigned short*)Cp)[(size_t)row * ldc + col] = f2bf(v);
                    else
                        ((float*)Cp)[(size_t)row * ldc + col] = v;
                }
            }
        }
}

// ------- fused: causal depthwise conv + SiLU  AND  dt softplus + chunk cumsum -------
#define NCONVB (ROWS * (CONVDIM / 8) / 256)   // 16896

__global__ __launch_bounds__(256) void convdt(
    const unsigned short* __restrict__ zx, const float* __restrict__ conv_w,
    const float* __restrict__ conv_b, unsigned short* __restrict__ xBC,
    const float* __restrict__ dt_bias, const float* __restrict__ A_log,
    float* __restrict__ dtb, float* __restrict__ cum, float* __restrict__ csum)
{
    __shared__ float ws4[4];
    if (blockIdx.x < NCONVB) {
        int idx = blockIdx.x * 256 + threadIdx.x;
        int g   = idx % (CONVDIM / 8);
        int row = idx / (CONVDIM / 8);
        int l   = row & (SEQ - 1);
        int ch0 = g * 8;
        const unsigned short* base = zx + (size_t)row * DINPROJ + DINNER + ch0;
        float s[8];
        float4 w4[8];
        #pragma unroll
        for (int c = 0; c < 8; ++c) {
            s[c]  = conv_b[ch0 + c];
            w4[c] = *reinterpret_cast<const float4*>(conv_w + (ch0 + c) * 4);
        }
        #pragma unroll
        for (int j = 0; j < 4; ++j) {
            int lj = l - 3 + j;
            if (lj >= 0) {
                ushort8 v = *reinterpret_cast<const ushort8*>(base + (long)(lj - l) * DINPROJ);
                #pragma unroll
                for (int c = 0; c < 8; ++c) {
                    float wj = (j == 0) ? w4[c].x : (j == 1) ? w4[c].y : (j == 2) ? w4[c].z : w4[c].w;
                    s[c] += wj * bf2f(v[c]);
                }
            }
        }
        ushort8 o;
        #pragma unroll
        for (int c = 0; c < 8; ++c) {
            float sig = 1.f / (1.f + __expf(-s[c]));
            o[c] = f2bf(s[c] * sig);
        }
        *reinterpret_cast<ushort8*>(xBC + (size_t)row * CONVDIM + ch0) = o;
    } else {
        int id = blockIdx.x - NCONVB;
        int h  = id & 31;
        int c  = (id >> 5) & 15;
        int b  = id >> 9;
        int t  = threadIdx.x;
        int row = b * SEQ + c * CHUNKL + t;
        float v = bf2f(zx[(size_t)row * DINPROJ + DINNER + CONVDIM + h]) + dt_bias[h];
        float dtv = (v > 20.f) ? v : log1pf(__expf(v));
        dtb[row * NHEADS + h] = dtv;
        float adt = -__expf(A_log[h]) * dtv;
        int lane = t & 63, wv = t >> 6;
        float s = adt;
        #pragma unroll
        for (int o = 1; o < 64; o <<= 1) {
            float x = __shfl_up(s, o, 64);
            if (lane >= o) s += x;
        }
        if (lane == 63) ws4[wv] = s;
        __syncthreads();
        float basev = 0.f;
        #pragma unroll
        for (int w = 0; w < 3; ++w)
            if (w < wv) basev += ws4[w];
        s += basev;
        cum[id * 256 + t] = s;
        if (t == 255) csum[id] = s;
    }
}

// ---------------- scores: S_raw[bc][l][s] = C[l].B[s] (head-independent) ----------------
__global__ __launch_bounds__(256) void score_kernel(
    const unsigned short* __restrict__ xBC, unsigned short* __restrict__ S_raw)
{
    int bc = blockIdx.x;        // 0..63 = b*16+c
    int sq = blockIdx.y;        // 0..3 s-quadrant
    int tid = threadIdx.x;
    int wave = tid >> 6, lane = tid & 63, q = lane >> 4, lm = lane & 15;
    __shared__ __align__(16) unsigned short Ct[256 * 72];
    __shared__ __align__(16) unsigned short Btl[64 * 72];

    #pragma unroll
    for (int i = 0; i < 8; ++i) {
        int idx = tid + 256 * i;
        int r = idx >> 3, ch = idx & 7;
        ushort8 v = *reinterpret_cast<const ushort8*>(
            &xBC[(size_t)(bc * 256 + r) * CONVDIM + DINNER + DSTATE + ch * 8]);
        *reinterpret_cast<ushort8*>(&Ct[r * 72 + ch * 8]) = v;
    }
    #pragma unroll
    for (int i = 0; i < 2; ++i) {
        int idx = tid + 256 * i;
        int r = idx >> 3, ch = idx & 7;
        ushort8 v = *reinterpret_cast<const ushort8*>(
            &xBC[(size_t)(bc * 256 + sq * 64 + r) * CONVDIM + DINNER + ch * 8]);
        *reinterpret_cast<ushort8*>(&Btl[r * 72 + ch * 8]) = v;
    }
    __syncthreads();

    floatx4 acc[4][4] = {};
    #pragma unroll
    for (int ks = 0; ks < 2; ++ks) {
        bf16x8 af[4], bfv[4];
        #pragma unroll
        for (int mt = 0; mt < 4; ++mt)
            af[mt] = *reinterpret_cast<const bf16x8*>(&Ct[(wave * 64 + mt * 16 + lm) * 72 + ks * 32 + q * 8]);
        #pragma unroll
        for (int nt = 0; nt < 4; ++nt)
            bfv[nt] = *reinterpret_cast<const bf16x8*>(&Btl[(nt * 16 + lm) * 72 + ks * 32 + q * 8]);
        #pragma unroll
        for (int mt = 0; mt < 4; ++mt)
            #pragma unroll
            for (int nt = 0; nt < 4; ++nt)
                acc[mt][nt] = __builtin_amdgcn_mfma_f32_16x16x32_bf16(af[mt], bfv[nt], acc[mt][nt], 0, 0, 0);
    }

    #pragma unroll
    for (int mt = 0; mt < 4; ++mt)
        #pragma unroll
        for (int nt = 0; nt < 4; ++nt) {
            int l = wave * 64 + mt * 16 + q * 4;
            int s = sq * 64 + nt * 16 + lm;
            #pragma unroll
            for (int r = 0; r < 4; ++r)
                S_raw[(size_t)(bc * 256 + l + r) * 256 + s] = f2bf(acc[mt][nt][r]);
        }
}

// ---------------- chunk states via MFMA + tr_read ----------------
__global__ __launch_bounds__(256) void states_kernel(
    const unsigned short* __restrict__ xBC, const float* __restrict__ dtb,
    const float* __restrict__ cum, float* __restrict__ states)
{
    int id = blockIdx.x;
    int h  = id & 31;
    int c  = (id >> 5) & 15;
    int b  = id >> 9;
    int tid = threadIdx.x;
    int wave = tid >> 6, lane = tid & 63, q = lane >> 4, lm = lane & 15;

    __shared__ float wls[256];
    __shared__ __align__(16) unsigned short Xs[16 * 8 * 72];   // [si][pi][4][16]+pad
    __shared__ __align__(16) unsigned short Bs[16 * 4 * 72];

    const int cumbase = id * 256;
    const int row0 = b * SEQ + c * CHUNKL;
    {
        float cumlast = cum[cumbase + 255];
        wls[tid] = __expf(cumlast - cum[cumbase + tid]) * dtb[(row0 + tid) * NHEADS + h];
    }

    floatx4 acc[2][4] = {};

    for (int sc = 0; sc < 4; ++sc) {
        const int s0 = sc * 64;
        __syncthreads();
        #pragma unroll
        for (int i = 0; i < 4; ++i) {
            int idx = tid + 256 * i;
            int sr = idx >> 4, ch = idx & 15;
            int row = row0 + s0 + sr;
            ushort8 v = *reinterpret_cast<const ushort8*>(
                &xBC[(size_t)row * CONVDIM + h * HEADDIM + ch * 8]);
            float w = wls[s0 + sr];
            ushort8 o;
            #pragma unroll
            for (int j = 0; j < 8; ++j) o[j] = f2bf(bf2f(v[j]) * w);
            int a = ((sr >> 2) * 8 + (ch >> 1)) * 72 + (sr & 3) * 16 + (ch & 1) * 8;
            *reinterpret_cast<ushort8*>(&Xs[a]) = o;
        }
        #pragma unroll
        for (int i = 0; i < 2; ++i) {
            int idx = tid + 256 * i;
            int sr = idx >> 3, ch = idx & 7;
            int row = row0 + s0 + sr;
            ushort8 v = *reinterpret_cast<const ushort8*>(
                &xBC[(size_t)row * CONVDIM + DINNER + ch * 8]);
            int a = ((sr >> 2) * 4 + (ch >> 1)) * 72 + (sr & 3) * 16 + (ch & 1) * 8;
            *reinterpret_cast<ushort8*>(&Bs[a]) = v;
        }
        __syncthreads();
        #pragma unroll
        for (int ks = 0; ks < 2; ++ks) {
            bf16x8 af[2], bfv[4];
            #pragma unroll
            for (int mt = 0; mt < 2; ++mt) {
                const unsigned short* vp = Xs + ((ks * 8 + 2 * q) * 8 + (wave * 2 + mt)) * 72 + lm * 4;
                U8tr u; u.v2[0] = tr16(vp); u.v2[1] = tr16(vp + 576);
                af[mt] = u.f;
            }
            #pragma unroll
            for (int nt = 0; nt < 4; ++nt) {
                const unsigned short* vp = Bs + ((ks * 8 + 2 * q) * 4 + nt) * 72 + lm * 4;
                U8tr u; u.v2[0] = tr16(vp); u.v2[1] = tr16(vp + 288);
                bfv[nt] = u.f;
            }
            asm volatile("s_waitcnt lgkmcnt(0)" ::: "memory");
            __builtin_amdgcn_sched_barrier(0);
            #pragma unroll
            for (int mt = 0; mt < 2; ++mt)
                #pragma unroll
                for (int nt = 0; nt < 4; ++nt)
                    acc[mt][nt] = __builtin_amdgcn_mfma_f32_16x16x32_bf16(af[mt], bfv[nt], acc[mt][nt], 0, 0, 0);
        }
    }

    #pragma unroll
    for (int mt = 0; mt < 2; ++mt)
        #pragma unroll
        for (int nt = 0; nt < 4; ++nt)
            #pragma unroll
            for (int r = 0; r < 4; ++r) {
                int p = wave * 32 + mt * 16 + q * 4 + r;
                int n = nt * 16 + lm;
                states[(size_t)id * 8192 + p * 64 + n] = acc[mt][nt][r];
            }
}

// ---------------- inter-chunk recurrence (in-place) ----------------
__global__ __launch_bounds__(256) void inter_kernel(
    float* __restrict__ states, const float* __restrict__ csum)
{
    int idx = blockIdx.x * 256 + threadIdx.x;
    int pn  = idx & 8191;
    int h   = (idx >> 13) & 31;
    int b   = idx >> 18;
    float S = 0.f;
    for (int c = 0; c < 16; ++c) {
        int id = (b * 16 + c) * 32 + h;
        size_t off = (size_t)id * 8192 + pn;
        float st = states[off];
        states[off] = S;
        S = S * __expf(csum[id]) + st;
    }
}

// ---------------- Y via MFMA: Y = P.Xdt + (C*efac).interS^T ----------------
__global__ __launch_bounds__(256) void y_mfma(
    const unsigned short* __restrict__ xBC,
    const unsigned short* __restrict__ S_raw,
    const float* __restrict__ dtb,
    const float* __restrict__ cum,
    const float* __restrict__ inter,
    unsigned short* __restrict__ zx)
{
    int id = blockIdx.x;               // (b*16+c)*32 + h
    int h  = id & 31;
    int bc = id >> 5;
    const int lh = blockIdx.y;         // 0/1 l-half
    int tid = threadIdx.x, wave = tid >> 6, lane = tid & 63, q = lane >> 4, lm = lane & 15;
    int wl = wave >> 1, wp = wave & 1;

    __shared__ float cums[256];
    __shared__ float dts[256];
    __shared__ __align__(16) unsigned short XdtT[128 * 72];   // subtiled Xdt or interS[p][72]
    __shared__ __align__(16) unsigned short PT[128 * 72];     // P[128][72]

    cums[tid] = cum[id * 256 + tid];
    dts[tid]  = dtb[(size_t)(bc * 256 + tid) * NHEADS + h];
    __syncthreads();

    floatx4 acc[4][4] = {};
    const int l0w = lh * 128 + wl * 64;
    const int nst = 2 * lh + 2;

    for (int st = 0; st < nst; ++st) {
        const int s0 = st * 64;
        __syncthreads();
        #pragma unroll
        for (int i = 0; i < 4; ++i) {
            int idx = tid + 256 * i;
            int sr = idx >> 4, ch = idx & 15;
            int srow = bc * 256 + s0 + sr;
            ushort8 v = *reinterpret_cast<const ushort8*>(
                &xBC[(size_t)srow * CONVDIM + h * HEADDIM + ch * 8]);
            float dt = dts[s0 + sr];
            ushort8 o;
            #pragma unroll
            for (int j = 0; j < 8; ++j) o[j] = f2bf(bf2f(v[j]) * dt);
            int a = ((sr >> 2) * 8 + (ch >> 1)) * 72 + (sr & 3) * 16 + (ch & 1) * 8;
            *reinterpret_cast<ushort8*>(&XdtT[a]) = o;
        }
        const int r0 = (s0 > lh * 128) ? 64 : 0;
        const int iters = (128 - r0) >> 5;
        for (int i = 0; i < iters; ++i) {
            int idx = tid + 256 * i;
            int r = r0 + (idx >> 3), ch = idx & 7;
            int l = lh * 128 + r;
            float cl = cums[l];
            ushort8 v = *reinterpret_cast<const ushort8*>(
                &S_raw[(size_t)(bc * 256 + l) * 256 + s0 + ch * 8]);
            ushort8 o;
            #pragma unroll
            for (int j = 0; j < 8; ++j) {
                int s = s0 + ch * 8 + j;
                float val = (s <= l) ? bf2f(v[j]) * __expf(cl - cums[s]) : 0.f;
                o[j] = f2bf(val);
            }
            *reinterpret_cast<ushort8*>(&PT[r * 72 + ch * 8]) = o;
        }
        __syncthreads();
        if (s0 <= l0w) {
            #pragma unroll
            for (int ks = 0; ks < 2; ++ks) {
                bf16x8 af[4], bfv[4];
                #pragma unroll
                for (int mt = 0; mt < 4; ++mt)
                    af[mt] = *reinterpret_cast<const bf16x8*>(
                        &PT[(wl * 64 + mt * 16 + lm) * 72 + ks * 32 + q * 8]);
                #pragma unroll
                for (int nt = 0; nt < 4; ++nt) {
                    const unsigned short* vp = XdtT + ((ks * 8 + 2 * q) * 8 + (wp * 4 + nt)) * 72 + lm * 4;
                    U8tr u; u.v2[0] = tr16(vp); u.v2[1] = tr16(vp + 576);
                    bfv[nt] = u.f;
                }
                asm volatile("s_waitcnt lgkmcnt(0)" ::: "memory");
                __builtin_amdgcn_sched_barrier(0);
                #pragma unroll
                for (int mt = 0; mt < 4; ++mt)
                    #pragma unroll
                    for (int nt = 0; nt < 4; ++nt)
                        acc[mt][nt] = __builtin_amdgcn_mfma_f32_16x16x32_bf16(af[mt], bfv[nt], acc[mt][nt], 0, 0, 0);
            }
        }
    }

    __syncthreads();
    {
        int p = tid >> 1, n0 = (tid & 1) * 32;
        const float* sp = &inter[(size_t)id * 8192 + p * 64 + n0];
        #pragma unroll
        for (int k2 = 0; k2 < 4; ++k2) {
            float4 a = *reinterpret_cast<const float4*>(sp + k2 * 8);
            float4 b2 = *reinterpret_cast<const float4*>(sp + k2 * 8 + 4);
            ushort8 o;
            o[0] = f2bf(a.x); o[1] = f2bf(a.y); o[2] = f2bf(a.z); o[3] = f2bf(a.w);
            o[4] = f2bf(b2.x); o[5] = f2bf(b2.y); o[6] = f2bf(b2.z); o[7] = f2bf(b2.w);
            *reinterpret_cast<ushort8*>(&XdtT[p * 72 + n0 + k2 * 8]) = o;
        }
        int r = tid >> 1;
        int l = lh * 128 + r;
        float ef = __expf(cums[l]);
        const unsigned short* cp = &xBC[(size_t)(bc * 256 + l) * CONVDIM + DINNER + DSTATE + n0];
        #pragma unroll
        for (int k2 = 0; k2 < 4; ++k2) {
            ushort8 v = *reinterpret_cast<const ushort8*>(cp + k2 * 8);
            ushort8 o;
            #pragma unroll
            for (int j = 0; j < 8; ++j) o[j] = f2bf(bf2f(v[j]) * ef);
            *reinterpret_cast<ushort8*>(&PT[r * 72 + n0 + k2 * 8]) = o;
        }
    }
    __syncthreads();
    #pragma unroll
    for (int ks = 0; ks < 2; ++ks) {
        bf16x8 af[4], bfv[4];
        #pragma unroll
        for (int mt = 0; mt < 4; ++mt)
            af[mt] = *reinterpret_cast<const bf16x8*>(
                &PT[(wl * 64 + mt * 16 + lm) * 72 + ks * 32 + q * 8]);
        #pragma unroll
        for (int nt = 0; nt < 4; ++nt)
            bfv[nt] = *reinterpret_cast<const bf16x8*>(
                &XdtT[(wp * 64 + nt * 16 + lm) * 72 + ks * 32 + q * 8]);
        #pragma unroll
        for (int mt = 0; mt < 4; ++mt)
            #pragma unroll
            for (int nt = 0; nt < 4; ++nt)
                acc[mt][nt] = __builtin_amdgcn_mfma_f32_16x16x32_bf16(af[mt], bfv[nt], acc[mt][nt], 0, 0, 0);
    }

    #pragma unroll
    for (int mt = 0; mt < 4; ++mt)
        #pragma unroll
        for (int nt = 0; nt < 4; ++nt) {
            int l = lh * 128 + wl * 64 + mt * 16 + q * 4;
            int pcol = wp * 64 + nt * 16 + lm;
            #pragma unroll
            for (int r = 0; r < 4; ++r)
                zx[(size_t)(bc * 256 + l + r) * DINPROJ + DINNER + h * HEADDIM + pcol]
                    = f2bf(acc[mt][nt][r]);
        }
}

// ------- fused: y*silu(z) + LayerNorm  AND  out_proj_w fp32->bf16 convert -------
__global__ __launch_bounds__(256) void gate_ln_cvt(
    unsigned short* __restrict__ zx, const float* __restrict__ ln_w,
    const float* __restrict__ ln_b,
    const float* __restrict__ w2, unsigned short* __restrict__ w2_bf)
{
    __shared__ float rs[256], rq[256];
    if (blockIdx.x >= ROWS) {
        cvt8(w2, w2_bf, ((blockIdx.x - ROWS) * 256 + threadIdx.x) * 8);
        return;
    }
    int row = blockIdx.x;
    int t   = threadIdx.x;
    size_t base = (size_t)row * DINPROJ;
    float g[16];
    float sum = 0.f, sumsq = 0.f;
    #pragma unroll
    for (int j = 0; j < 2; ++j) {
        int i = t * 8 + j * 2048;
        ushort8 zv = *reinterpret_cast<const ushort8*>(zx + base + i);
        ushort8 yv = *reinterpret_cast<const ushort8*>(zx + base + DINNER + i);
        #pragma unroll
        for (int k = 0; k < 8; ++k) {
            float z = bf2f(zv[k]);
            float y = bf2f(yv[k]);
            float sig = 1.f / (1.f + __expf(-z));
            float v = y * z * sig;
            g[j * 8 + k] = v;
            sum += v; sumsq += v * v;
        }
    }
    rs[t] = sum; rq[t] = sumsq;
    __syncthreads();
    for (int off = 128; off > 0; off >>= 1) {
        if (t < off) { rs[t] += rs[t + off]; rq[t] += rq[t + off]; }
        __syncthreads();
    }
    float mu   = rs[0] * (1.f / DINNER);
    float var  = rq[0] * (1.f / DINNER) - mu * mu;
    float rstd = rsqrtf(var + 1e-5f);
    #pragma unroll
    for (int j = 0; j < 2; ++j) {
        int i = t * 8 + j * 2048;
        ushort8 o;
        #pragma unroll
        for (int k = 0; k < 8; ++k)
            o[k] = f2bf((g[j * 8 + k] - mu) * rstd * ln_w[i + k] + ln_b[i + k]);
        *reinterpret_cast<ushort8*>(zx + base + DINNER + i) = o;
    }
}

extern "C" void kernel_launch(void* const* d_in, const int* in_sizes, int n_in,
                              void* d_out, int out_size, void* d_ws, size_t ws_size,
                              hipStream_t stream)
{
    const float* u          = (const float*)d_in[0];
    const float* in_proj_w  = (const float*)d_in[1];
    const float* in_proj_b  = (const float*)d_in[2];
    const float* conv_w     = (const float*)d_in[3];
    const float* conv_b     = (const float*)d_in[4];
    const float* dt_bias    = (const float*)d_in[5];
    const float* A_log      = (const float*)d_in[6];
    const float* ln_w       = (const float*)d_in[7];
    const float* ln_b       = (const float*)d_in[8];
    const float* out_proj_w = (const float*)d_in[9];
    const float* out_proj_b = (const float*)d_in[10];
    float* out = (float*)d_out;

    // workspace layout (~238.5 MiB)
    unsigned short* zx  = (unsigned short*)d_ws;              // ROWS*DINPROJ bf16
    unsigned short* xBC = zx + (size_t)ROWS * DINPROJ;        // ROWS*CONVDIM bf16
    float* dtb    = (float*)(xBC + (size_t)ROWS * CONVDIM);   // ROWS*NHEADS f32
    float* cum    = dtb + (size_t)ROWS * NHEADS;              // ROWS*NHEADS f32
    float* csum   = cum + (size_t)ROWS * NHEADS;              // 1024 f32
    float* states = csum + 1024;                              // 1024*8192 f32
    unsigned short* S_raw = (unsigned short*)(states + (size_t)1024 * 8192); // 64*256*256 bf16

    // aliases (no live overlap):
    unsigned short* u_bf  = (unsigned short*)states;          // dead after gemm_in
    unsigned short* w1_bf = xBC;                              // dead after gemm_in
    unsigned short* w2_bf = (unsigned short*)states;          // born after y_mfma

    static bool attr_done = false;
    if (!attr_done) {
        hipFuncSetAttribute(reinterpret_cast<const void*>(&gemm256<1>),
                            hipFuncAttributeMaxDynamicSharedMemorySize, 131072);
        hipFuncSetAttribute(reinterpret_cast<const void*>(&gemm256<0>),
                            hipFuncAttributeMaxDynamicSharedMemorySize, 131072);
        attr_done = true;
    }

    dim3 blk(256);

    const int NBU  = (ROWS * DMODEL) / 2048;      // 8192
    const int NBW1 = (DINPROJ * DMODEL) / 2048;   // 8352
    f32_to_bf16_2<<<dim3(NBU + NBW1), blk, 0, stream>>>(u, u_bf, NBU, in_proj_w, w1_bf);

    gemm256<1><<<dim3((ROWS / 256) * ((DINPROJ + 255) / 256)), dim3(512), 131072, stream>>>(
        u_bf, DMODEL, w1_bf, DMODEL, in_proj_b, (void*)zx, DINPROJ, ROWS, DINPROJ, DMODEL);

    convdt<<<dim3(NCONVB + BATCH * NCHUNK * NHEADS), blk, 0, stream>>>(
        zx, conv_w, conv_b, xBC, dt_bias, A_log, dtb, cum, csum);

    score_kernel<<<dim3(BATCH * NCHUNK, 4), blk, 0, stream>>>(xBC, S_raw);

    states_kernel<<<dim3(BATCH * NCHUNK * NHEADS), blk, 0, stream>>>(xBC, dtb, cum, states);

    inter_kernel<<<dim3((BATCH * NHEADS * 8192) / 256), blk, 0, stream>>>(states, csum);

    y_mfma<<<dim3(BATCH * NCHUNK * NHEADS, 2), blk, 0, stream>>>(xBC, S_raw, dtb, cum, states, zx);

    gate_ln_cvt<<<dim3(ROWS + (DMODEL * DINNER) / 2048), blk, 0, stream>>>(
        zx, ln_w, ln_b, out_proj_w, w2_bf);

    gemm256<0><<<dim3((ROWS / 256) * (DMODEL / 256)), dim3(512), 131072, stream>>>(
        (const unsigned short*)(zx + DINNER), DINPROJ, w2_bf, DINNER, out_proj_b, (void*)out,
        DMODEL, ROWS, DMODEL, DINNER);
}

// Round 9
// 768.408 us; speedup vs baseline: 1.2164x; 1.1571x over previous
//
#include <hip/hip_runtime.h>
#include <math.h>

#define BATCH    2
#define SEQ      4096
#define DMODEL   2048
#define DSTATE   64
#define HEADDIM  128
#define NHEADS   32
#define DINNER   4096
#define CONVDIM  4224
#define DINPROJ  8352
#define NCHUNK   16
#define CHUNKL   256
#define ROWS     (BATCH*SEQ)   // 8192

typedef __attribute__((ext_vector_type(8))) __bf16 bf16x8;
typedef __attribute__((ext_vector_type(4))) float floatx4;
typedef __attribute__((ext_vector_type(8))) unsigned short ushort8;
typedef __attribute__((ext_vector_type(2))) unsigned int uint2v;

__device__ __forceinline__ unsigned short f2bf(float f) {
    union { float f; unsigned int u; } v; v.f = f;
    unsigned int u = v.u;
    unsigned int r = (u + 0x7FFFu + ((u >> 16) & 1u)) >> 16;
    return (unsigned short)r;
}
__device__ __forceinline__ float bf2f(unsigned short s) {
    union { unsigned int u; float f; } v; v.u = ((unsigned int)s) << 16;
    return v.f;
}

__device__ __forceinline__ void gload_lds16(const unsigned short* g, unsigned short* lds) {
    __builtin_amdgcn_global_load_lds(
        (const __attribute__((address_space(1))) unsigned int*)g,
        (__attribute__((address_space(3))) unsigned int*)lds,
        16, 0, 0);
}

// hardware transpose read (verified by refcheck r7)
__device__ __forceinline__ uint2v tr16(const unsigned short* p) {
    uint2v d;
    asm volatile("ds_read_b64_tr_b16 %0, %1"
                 : "=v"(d)
                 : "v"((const __attribute__((address_space(3))) unsigned short*)p));
    return d;
}
union U8tr { uint2v v2[2]; bf16x8 f; };

__device__ __forceinline__ void cvt8(const float* s, unsigned short* d, int i) {
    float4 a = *reinterpret_cast<const float4*>(s + i);
    float4 b = *reinterpret_cast<const float4*>(s + i + 4);
    ushort8 o;
    o[0] = f2bf(a.x); o[1] = f2bf(a.y); o[2] = f2bf(a.z); o[3] = f2bf(a.w);
    o[4] = f2bf(b.x); o[5] = f2bf(b.y); o[6] = f2bf(b.z); o[7] = f2bf(b.w);
    *reinterpret_cast<ushort8*>(d + i) = o;
}

// ---------------- fused fp32 -> bf16 convert (u + in_proj_w) ----------------
__global__ __launch_bounds__(256) void f32_to_bf16_2(
    const float* __restrict__ s0, unsigned short* __restrict__ d0, int nb0,
    const float* __restrict__ s1, unsigned short* __restrict__ d1)
{
    int b = blockIdx.x;
    if (b < nb0) {
        cvt8(s0, d0, (b * 256 + threadIdx.x) * 8);
    } else {
        cvt8(s1, d1, ((b - nb0) * 256 + threadIdx.x) * 8);
    }
}

// ==================== 256x256 8-phase pipelined GEMM v5 ====================
// v5: SINGLE barrier per phase ({reads; stage; MFMA; [vmcnt]; barrier}).
// The pre-MFMA barrier was not load-bearing: ds_reads are wave-private
// (compiler waitcnt covers register deps); STAGE-vs-read races are prevented
// by the end-barrier chain (every STAGE targets a region whose last reader's
// consuming MFMA completed >=1 end-barrier earlier). vmcnt(6) issue-order
// math unchanged. Grouped raster (GROUP_M=8) + XCD swizzle kept (FETCH 2.5x
// win, r8); dead-column wave skip kept.

#define STAGE(G, ldg, grow0, clampmax, k0, off)                                 \
  { int r0_ = (grow0) + sr0; int r1_ = (grow0) + sr1;                           \
    if ((clampmax) >= 0) { if (r0_ > (clampmax)) r0_ = (clampmax);              \
                           if (r1_ > (clampmax)) r1_ = (clampmax); }            \
    unsigned short* d_ = smem + (off) + ldsw;                                   \
    gload_lds16((G) + (size_t)r0_ * (ldg) + (k0) + sc0, d_);                    \
    gload_lds16((G) + (size_t)r1_ * (ldg) + (k0) + sc1, d_ + 4096); }

__device__ __forceinline__ void rd_a(bf16x8 (&dst)[4][2], const unsigned short* base) {
    #pragma unroll
    for (int mt = 0; mt < 4; ++mt)
        #pragma unroll
        for (int ks = 0; ks < 2; ++ks)
            dst[mt][ks] = *reinterpret_cast<const bf16x8*>(base + (mt * 2 + ks) * 512);
}
__device__ __forceinline__ void rd_b(bf16x8 (&dst)[2][2], const unsigned short* base) {
    #pragma unroll
    for (int nt = 0; nt < 2; ++nt)
        #pragma unroll
        for (int ks = 0; ks < 2; ++ks)
            dst[nt][ks] = *reinterpret_cast<const bf16x8*>(base + (nt * 2 + ks) * 512);
}

template<int R0, int C0>
__device__ __forceinline__ void mfma_q(floatx4 (&acc)[8][4],
                                       const bf16x8 (&a)[4][2],
                                       const bf16x8 (&b)[2][2])
{
    #pragma unroll
    for (int mt = 0; mt < 4; ++mt)
        #pragma unroll
        for (int nt = 0; nt < 2; ++nt) {
            acc[R0+mt][C0+nt] = __builtin_amdgcn_mfma_f32_16x16x32_bf16(a[mt][0], b[nt][0], acc[R0+mt][C0+nt], 0, 0, 0);
            acc[R0+mt][C0+nt] = __builtin_amdgcn_mfma_f32_16x16x32_bf16(a[mt][1], b[nt][1], acc[R0+mt][C0+nt], 0, 0, 0);
        }
}

#define MQ(R0, C0, A_, B_)                          \
    __builtin_amdgcn_s_setprio(1);                  \
    if (alive) mfma_q<R0, C0>(acc, A_, B_);         \
    __builtin_amdgcn_s_setprio(0);

template<int OUT_BF16>
__global__ __launch_bounds__(512, 2) void gemm256(
    const unsigned short* __restrict__ A, int lda,
    const unsigned short* __restrict__ Bt, int ldb,
    const float* __restrict__ bias,
    void* __restrict__ Cp, int ldc,
    int M, int N, int K)
{
    extern __shared__ __align__(16) unsigned short smem[];
    const int tid  = threadIdx.x;
    const int wave = tid >> 6;
    const int lane = tid & 63;
    const int q    = lane >> 4;
    const int lm   = lane & 15;
    const int wm   = wave >> 2;
    const int wn   = wave & 3;
    const int bh   = wn >> 1;
    const int bn2  = wn & 1;

    const int cpx = gridDim.x >> 3;
    const int sid = (blockIdx.x & 7) * cpx + (blockIdx.x >> 3);
    const int nbm = M >> 8;
    const int nbn = gridDim.x / nbm;
    int bm, bn;
    {
        const int GM = 8;
        int nig = GM * nbn;
        int grp = sid / nig;
        int first = grp * GM;
        int gsz = nbm - first; if (gsz > GM) gsz = GM;
        bm = first + (sid % nig) % gsz;
        bn = (sid % nig) / gsz;
    }
    const int arow0 = bm * 256;
    const int brow0 = bn * 256;
    const bool alive = (brow0 + wn * 64) < N;

    int sr0, sc0, sr1, sc1;
    {
        int L = tid << 4;
        int b = L & 1023; b ^= ((b >> 9) & 1) << 5;
        int sub = L >> 10;
        sr0 = ((sub >> 1) << 4) | (b >> 6);
        sc0 = ((sub & 1) << 5) | ((b & 63) >> 1);
        L = 8192 | (tid << 4);
        b = L & 1023; b ^= ((b >> 9) & 1) << 5;
        sub = L >> 10;
        sr1 = ((sub >> 1) << 4) | (b >> 6);
        sc1 = ((sub & 1) << 5) | ((b & 63) >> 1);
    }
    const int ldsw = wave * 512;
    const int lhw = ((((lm << 6) | (q << 4)) ^ ((lm & 8) << 2)) >> 1);
    const int NT  = K >> 6;
    const int NM1 = N - 1;

    STAGE(A,  lda, arow0,       -1,  0,  0);
    STAGE(A,  lda, arow0 + 128, -1,  0,  8192);
    STAGE(Bt, ldb, brow0,       NM1, 0,  16384);
    STAGE(Bt, ldb, brow0 + 128, NM1, 0,  24576);
    STAGE(Bt, ldb, brow0,       NM1, 64, 32768 + 16384);
    STAGE(Bt, ldb, brow0 + 128, NM1, 64, 32768 + 24576);
    STAGE(A,  lda, arow0,       -1,  64, 32768);
    STAGE(A,  lda, arow0 + 128, -1,  64, 32768 + 8192);
    asm volatile("s_waitcnt vmcnt(8)" ::: "memory");
    __builtin_amdgcn_s_barrier();

    const unsigned short* Ab0 = smem + wm * 8192 + lhw;
    const unsigned short* Bb0 = smem + 16384 + bh * 8192 + bn2 * 4096 + lhw;
    const unsigned short* Ab1 = Ab0 + 32768;
    const unsigned short* Bb1 = Bb0 + 32768;

    bf16x8 a_lo[4][2], a_hi[4][2], b_lo[2][2], b_hi[2][2];
    rd_a(a_lo, Ab0);
    rd_b(b_lo, Bb0);

    floatx4 acc[8][4] = {};
    const int NI = NT >> 1;

    for (int i = 0; i < NI; ++i) {
        int tE2 = 2 * i + 2; if (tE2 > NT - 1) tE2 = NT - 1;
        int tO2 = 2 * i + 3; if (tO2 > NT - 1) tO2 = NT - 1;
        const int kE = tE2 << 6, kO = tO2 << 6;

        // P1: read qb1(E); MFMA Q00(E)
        rd_b(b_hi, Bb0 + 2048);
        MQ(0, 0, a_lo, b_lo);
        __builtin_amdgcn_s_barrier();

        // P2: read qa1(E); stage B-h0(E+2); MFMA Q01(E)
        rd_a(a_hi, Ab0 + 4096);
        STAGE(Bt, ldb, brow0, NM1, kE, 16384);
        MQ(0, 2, a_lo, b_hi);
        __builtin_amdgcn_s_barrier();

        // P3: stage B-h1(E+2) + A-h0(E+2); MFMA Q11(E); drain tile O (vmcnt 6)
        STAGE(Bt, ldb, brow0 + 128, NM1, kE, 24576);
        STAGE(A,  lda, arow0,       -1,  kE, 0);
        MQ(4, 2, a_hi, b_hi);
        asm volatile("s_waitcnt vmcnt(6)" ::: "memory");
        __builtin_amdgcn_s_barrier();

        // P4: read qa0(O)+qb0(O); stage A-h1(E+2); MFMA Q10(E)
        rd_a(a_lo, Ab1);
        rd_b(b_hi, Bb1);
        STAGE(A, lda, arow0 + 128, -1, kE, 8192);
        MQ(4, 0, a_hi, b_lo);
        __builtin_amdgcn_s_barrier();

        // P5: read qb1(O); MFMA Q00(O)
        rd_b(b_lo, Bb1 + 2048);
        MQ(0, 0, a_lo, b_hi);
        __builtin_amdgcn_s_barrier();

        // P6: read qa1(O); stage B-h0(O+2); MFMA Q01(O)
        rd_a(a_hi, Ab1 + 4096);
        STAGE(Bt, ldb, brow0, NM1, kO, 32768 + 16384);
        MQ(0, 2, a_lo, b_lo);
        __builtin_amdgcn_s_barrier();

        // P7: stage B-h1(O+2) + A-h0(O+2); MFMA Q11(O); drain tile E+2 (vmcnt 6)
        STAGE(Bt, ldb, brow0 + 128, NM1, kO, 32768 + 24576);
        STAGE(A,  lda, arow0,       -1,  kO, 32768);
        MQ(4, 2, a_hi, b_lo);
        asm volatile("s_waitcnt vmcnt(6)" ::: "memory");
        __builtin_amdgcn_s_barrier();

        // P8: read qa0(E')+qb0(E'); stage A-h1(O+2); MFMA Q10(O)
        rd_a(a_lo, Ab0);
        rd_b(b_lo, Bb0);
        STAGE(A, lda, arow0 + 128, -1, kO, 32768 + 8192);
        MQ(4, 0, a_hi, b_hi);
        __builtin_amdgcn_s_barrier();
    }

    asm volatile("s_waitcnt vmcnt(0)" ::: "memory");

    const int row0 = arow0 + wm * 128;
    const int col0 = brow0 + wn * 64;
    #pragma unroll
    for (int mt = 0; mt < 8; ++mt)
        #pragma unroll
        for (int nt = 0; nt < 4; ++nt) {
            int col = col0 + nt * 16 + lm;
            if (col < N) {
                float bv = bias[col];
                #pragma unroll
                for (int r = 0; r < 4; ++r) {
                    int row = row0 + mt * 16 + q * 4 + r;
                    float v = acc[mt][nt][r] + bv;
                    if (OUT_BF16)
                        ((unsigned short*)Cp)[(size_t)row * ldc + col] = f2bf(v);
                    else
                        ((float*)Cp)[(size_t)row * ldc + col] = v;
                }
            }
        }
}

// ------- fused: causal depthwise conv + SiLU (4 rows/thread)  AND  dt+cumsum -------
// conv: 7 row-loads per 4 outputs (was 16) — ~2.3x less L2 read traffic.
#define NCONVB ((ROWS / 4) * (CONVDIM / 8) / 256)   // 4224

__global__ __launch_bounds__(256) void convdt(
    const unsigned short* __restrict__ zx, const float* __restrict__ conv_w,
    const float* __restrict__ conv_b, unsigned short* __restrict__ xBC,
    const float* __restrict__ dt_bias, const float* __restrict__ A_log,
    float* __restrict__ dtb, float* __restrict__ cum, float* __restrict__ csum)
{
    __shared__ float ws4[4];
    if (blockIdx.x < NCONVB) {
        int idx = blockIdx.x * 256 + threadIdx.x;
        int g   = idx % (CONVDIM / 8);
        int rb  = idx / (CONVDIM / 8);
        int r0  = rb * 4;                  // 4-aligned; SEQ%4==0 -> same batch
        int l0  = r0 & (SEQ - 1);
        int ch0 = g * 8;
        const unsigned short* base = zx + (size_t)r0 * DINPROJ + DINNER + ch0;
        float4 w4[8];
        float bsv[8];
        #pragma unroll
        for (int c = 0; c < 8; ++c) {
            w4[c]  = *reinterpret_cast<const float4*>(conv_w + (ch0 + c) * 4);
            bsv[c] = conv_b[ch0 + c];
        }
        float vv[7][8];
        #pragma unroll
        for (int j = 0; j < 7; ++j) {
            int lj = l0 - 3 + j;
            if (lj >= 0) {
                ushort8 v = *reinterpret_cast<const ushort8*>(base + (long)(j - 3) * DINPROJ);
                #pragma unroll
                for (int c = 0; c < 8; ++c) vv[j][c] = bf2f(v[c]);
            } else {
                #pragma unroll
                for (int c = 0; c < 8; ++c) vv[j][c] = 0.f;
            }
        }
        #pragma unroll
        for (int i = 0; i < 4; ++i) {
            ushort8 o;
            #pragma unroll
            for (int c = 0; c < 8; ++c) {
                float s = bsv[c] + w4[c].x * vv[i][c] + w4[c].y * vv[i + 1][c]
                                 + w4[c].z * vv[i + 2][c] + w4[c].w * vv[i + 3][c];
                float sig = 1.f / (1.f + __expf(-s));
                o[c] = f2bf(s * sig);
            }
            *reinterpret_cast<ushort8*>(xBC + (size_t)(r0 + i) * CONVDIM + ch0) = o;
        }
    } else {
        int id = blockIdx.x - NCONVB;
        int h  = id & 31;
        int c  = (id >> 5) & 15;
        int b  = id >> 9;
        int t  = threadIdx.x;
        int row = b * SEQ + c * CHUNKL + t;
        float v = bf2f(zx[(size_t)row * DINPROJ + DINNER + CONVDIM + h]) + dt_bias[h];
        float dtv = (v > 20.f) ? v : log1pf(__expf(v));
        dtb[row * NHEADS + h] = dtv;
        float adt = -__expf(A_log[h]) * dtv;
        int lane = t & 63, wv = t >> 6;
        float s = adt;
        #pragma unroll
        for (int o = 1; o < 64; o <<= 1) {
            float x = __shfl_up(s, o, 64);
            if (lane >= o) s += x;
        }
        if (lane == 63) ws4[wv] = s;
        __syncthreads();
        float basev = 0.f;
        #pragma unroll
        for (int w = 0; w < 3; ++w)
            if (w < wv) basev += ws4[w];
        s += basev;
        cum[id * 256 + t] = s;
        if (t == 255) csum[id] = s;
    }
}

// ---------------- scores: S_raw[bc][l][s] = C[l].B[s] (head-independent) ----------------
__global__ __launch_bounds__(256) void score_kernel(
    const unsigned short* __restrict__ xBC, unsigned short* __restrict__ S_raw)
{
    int bc = blockIdx.x;        // 0..63 = b*16+c
    int sq = blockIdx.y;        // 0..3 s-quadrant
    int tid = threadIdx.x;
    int wave = tid >> 6, lane = tid & 63, q = lane >> 4, lm = lane & 15;
    __shared__ __align__(16) unsigned short Ct[256 * 72];
    __shared__ __align__(16) unsigned short Btl[64 * 72];

    #pragma unroll
    for (int i = 0; i < 8; ++i) {
        int idx = tid + 256 * i;
        int r = idx >> 3, ch = idx & 7;
        ushort8 v = *reinterpret_cast<const ushort8*>(
            &xBC[(size_t)(bc * 256 + r) * CONVDIM + DINNER + DSTATE + ch * 8]);
        *reinterpret_cast<ushort8*>(&Ct[r * 72 + ch * 8]) = v;
    }
    #pragma unroll
    for (int i = 0; i < 2; ++i) {
        int idx = tid + 256 * i;
        int r = idx >> 3, ch = idx & 7;
        ushort8 v = *reinterpret_cast<const ushort8*>(
            &xBC[(size_t)(bc * 256 + sq * 64 + r) * CONVDIM + DINNER + ch * 8]);
        *reinterpret_cast<ushort8*>(&Btl[r * 72 + ch * 8]) = v;
    }
    __syncthreads();

    floatx4 acc[4][4] = {};
    #pragma unroll
    for (int ks = 0; ks < 2; ++ks) {
        bf16x8 af[4], bfv[4];
        #pragma unroll
        for (int mt = 0; mt < 4; ++mt)
            af[mt] = *reinterpret_cast<const bf16x8*>(&Ct[(wave * 64 + mt * 16 + lm) * 72 + ks * 32 + q * 8]);
        #pragma unroll
        for (int nt = 0; nt < 4; ++nt)
            bfv[nt] = *reinterpret_cast<const bf16x8*>(&Btl[(nt * 16 + lm) * 72 + ks * 32 + q * 8]);
        #pragma unroll
        for (int mt = 0; mt < 4; ++mt)
            #pragma unroll
            for (int nt = 0; nt < 4; ++nt)
                acc[mt][nt] = __builtin_amdgcn_mfma_f32_16x16x32_bf16(af[mt], bfv[nt], acc[mt][nt], 0, 0, 0);
    }

    #pragma unroll
    for (int mt = 0; mt < 4; ++mt)
        #pragma unroll
        for (int nt = 0; nt < 4; ++nt) {
            int l = wave * 64 + mt * 16 + q * 4;
            int s = sq * 64 + nt * 16 + lm;
            #pragma unroll
            for (int r = 0; r < 4; ++r)
                S_raw[(size_t)(bc * 256 + l + r) * 256 + s] = f2bf(acc[mt][nt][r]);
        }
}

// ---------------- chunk states via MFMA + tr_read ----------------
__global__ __launch_bounds__(256) void states_kernel(
    const unsigned short* __restrict__ xBC, const float* __restrict__ dtb,
    const float* __restrict__ cum, float* __restrict__ states)
{
    int id = blockIdx.x;
    int h  = id & 31;
    int c  = (id >> 5) & 15;
    int b  = id >> 9;
    int tid = threadIdx.x;
    int wave = tid >> 6, lane = tid & 63, q = lane >> 4, lm = lane & 15;

    __shared__ float wls[256];
    __shared__ __align__(16) unsigned short Xs[16 * 8 * 72];   // [si][pi][4][16]+pad
    __shared__ __align__(16) unsigned short Bs[16 * 4 * 72];

    const int cumbase = id * 256;
    const int row0 = b * SEQ + c * CHUNKL;
    {
        float cumlast = cum[cumbase + 255];
        wls[tid] = __expf(cumlast - cum[cumbase + tid]) * dtb[(row0 + tid) * NHEADS + h];
    }

    floatx4 acc[2][4] = {};

    for (int sc = 0; sc < 4; ++sc) {
        const int s0 = sc * 64;
        __syncthreads();
        #pragma unroll
        for (int i = 0; i < 4; ++i) {
            int idx = tid + 256 * i;
            int sr = idx >> 4, ch = idx & 15;
            int row = row0 + s0 + sr;
            ushort8 v = *reinterpret_cast<const ushort8*>(
                &xBC[(size_t)row * CONVDIM + h * HEADDIM + ch * 8]);
            float w = wls[s0 + sr];
            ushort8 o;
            #pragma unroll
            for (int j = 0; j < 8; ++j) o[j] = f2bf(bf2f(v[j]) * w);
            int a = ((sr >> 2) * 8 + (ch >> 1)) * 72 + (sr & 3) * 16 + (ch & 1) * 8;
            *reinterpret_cast<ushort8*>(&Xs[a]) = o;
        }
        #pragma unroll
        for (int i = 0; i < 2; ++i) {
            int idx = tid + 256 * i;
            int sr = idx >> 3, ch = idx & 7;
            int row = row0 + s0 + sr;
            ushort8 v = *reinterpret_cast<const ushort8*>(
                &xBC[(size_t)row * CONVDIM + DINNER + ch * 8]);
            int a = ((sr >> 2) * 4 + (ch >> 1)) * 72 + (sr & 3) * 16 + (ch & 1) * 8;
            *reinterpret_cast<ushort8*>(&Bs[a]) = v;
        }
        __syncthreads();
        #pragma unroll
        for (int ks = 0; ks < 2; ++ks) {
            bf16x8 af[2], bfv[4];
            #pragma unroll
            for (int mt = 0; mt < 2; ++mt) {
                const unsigned short* vp = Xs + ((ks * 8 + 2 * q) * 8 + (wave * 2 + mt)) * 72 + lm * 4;
                U8tr u; u.v2[0] = tr16(vp); u.v2[1] = tr16(vp + 576);
                af[mt] = u.f;
            }
            #pragma unroll
            for (int nt = 0; nt < 4; ++nt) {
                const unsigned short* vp = Bs + ((ks * 8 + 2 * q) * 4 + nt) * 72 + lm * 4;
                U8tr u; u.v2[0] = tr16(vp); u.v2[1] = tr16(vp + 288);
                bfv[nt] = u.f;
            }
            asm volatile("s_waitcnt lgkmcnt(0)" ::: "memory");
            __builtin_amdgcn_sched_barrier(0);
            #pragma unroll
            for (int mt = 0; mt < 2; ++mt)
                #pragma unroll
                for (int nt = 0; nt < 4; ++nt)
                    acc[mt][nt] = __builtin_amdgcn_mfma_f32_16x16x32_bf16(af[mt], bfv[nt], acc[mt][nt], 0, 0, 0);
        }
    }

    #pragma unroll
    for (int mt = 0; mt < 2; ++mt)
        #pragma unroll
        for (int nt = 0; nt < 4; ++nt)
            #pragma unroll
            for (int r = 0; r < 4; ++r) {
                int p = wave * 32 + mt * 16 + q * 4 + r;
                int n = nt * 16 + lm;
                states[(size_t)id * 8192 + p * 64 + n] = acc[mt][nt][r];
            }
}

// ---------------- inter-chunk recurrence (in-place, preloaded) ----------------
__global__ __launch_bounds__(256) void inter_kernel(
    float* __restrict__ states, const float* __restrict__ csum)
{
    int idx = blockIdx.x * 256 + threadIdx.x;
    int pn  = idx & 8191;
    int h   = (idx >> 13) & 31;
    int b   = idx >> 18;
    float st[16];
    #pragma unroll
    for (int c = 0; c < 16; ++c)
        st[c] = states[(size_t)((b * 16 + c) * 32 + h) * 8192 + pn];
    float S = 0.f;
    #pragma unroll
    for (int c = 0; c < 16; ++c) {
        int id = (b * 16 + c) * 32 + h;
        states[(size_t)id * 8192 + pn] = S;
        S = S * __expf(csum[id]) + st[c];
    }
}

// ---------------- Y via MFMA: Y = P.Xdt + (C*efac).interS^T ----------------
__global__ __launch_bounds__(256) void y_mfma(
    const unsigned short* __restrict__ xBC,
    const unsigned short* __restrict__ S_raw,
    const float* __restrict__ dtb,
    const float* __restrict__ cum,
    const float* __restrict__ inter,
    unsigned short* __restrict__ zx)
{
    int id = blockIdx.x;               // (b*16+c)*32 + h
    int h  = id & 31;
    int bc = id >> 5;
    const int lh = blockIdx.y;         // 0/1 l-half
    int tid = threadIdx.x, wave = tid >> 6, lane = tid & 63, q = lane >> 4, lm = lane & 15;
    int wl = wave >> 1, wp = wave & 1;

    __shared__ float cums[256];
    __shared__ float dts[256];
    __shared__ __align__(16) unsigned short XdtT[128 * 72];   // subtiled Xdt or interS[p][72]
    __shared__ __align__(16) unsigned short PT[128 * 72];     // P[128][72]

    cums[tid] = cum[id * 256 + tid];
    dts[tid]  = dtb[(size_t)(bc * 256 + tid) * NHEADS + h];
    __syncthreads();

    floatx4 acc[4][4] = {};
    const int l0w = lh * 128 + wl * 64;
    const int nst = 2 * lh + 2;

    for (int st = 0; st < nst; ++st) {
        const int s0 = st * 64;
        __syncthreads();
        #pragma unroll
        for (int i = 0; i < 4; ++i) {
            int idx = tid + 256 * i;
            int sr = idx >> 4, ch = idx & 15;
            int srow = bc * 256 + s0 + sr;
            ushort8 v = *reinterpret_cast<const ushort8*>(
                &xBC[(size_t)srow * CONVDIM + h * HEADDIM + ch * 8]);
            float dt = dts[s0 + sr];
            ushort8 o;
            #pragma unroll
            for (int j = 0; j < 8; ++j) o[j] = f2bf(bf2f(v[j]) * dt);
            int a = ((sr >> 2) * 8 + (ch >> 1)) * 72 + (sr & 3) * 16 + (ch & 1) * 8;
            *reinterpret_cast<ushort8*>(&XdtT[a]) = o;
        }
        const int r0 = (s0 > lh * 128) ? 64 : 0;
        const int iters = (128 - r0) >> 5;
        for (int i = 0; i < iters; ++i) {
            int idx = tid + 256 * i;
            int r = r0 + (idx >> 3), ch = idx & 7;
            int l = lh * 128 + r;
            float cl = cums[l];
            ushort8 v = *reinterpret_cast<const ushort8*>(
                &S_raw[(size_t)(bc * 256 + l) * 256 + s0 + ch * 8]);
            ushort8 o;
            #pragma unroll
            for (int j = 0; j < 8; ++j) {
                int s = s0 + ch * 8 + j;
                float val = (s <= l) ? bf2f(v[j]) * __expf(cl - cums[s]) : 0.f;
                o[j] = f2bf(val);
            }
            *reinterpret_cast<ushort8*>(&PT[r * 72 + ch * 8]) = o;
        }
        __syncthreads();
        if (s0 <= l0w) {
            #pragma unroll
            for (int ks = 0; ks < 2; ++ks) {
                bf16x8 af[4], bfv[4];
                #pragma unroll
                for (int mt = 0; mt < 4; ++mt)
                    af[mt] = *reinterpret_cast<const bf16x8*>(
                        &PT[(wl * 64 + mt * 16 + lm) * 72 + ks * 32 + q * 8]);
                #pragma unroll
                for (int nt = 0; nt < 4; ++nt) {
                    const unsigned short* vp = XdtT + ((ks * 8 + 2 * q) * 8 + (wp * 4 + nt)) * 72 + lm * 4;
                    U8tr u; u.v2[0] = tr16(vp); u.v2[1] = tr16(vp + 576);
                    bfv[nt] = u.f;
                }
                asm volatile("s_waitcnt lgkmcnt(0)" ::: "memory");
                __builtin_amdgcn_sched_barrier(0);
                #pragma unroll
                for (int mt = 0; mt < 4; ++mt)
                    #pragma unroll
                    for (int nt = 0; nt < 4; ++nt)
                        acc[mt][nt] = __builtin_amdgcn_mfma_f32_16x16x32_bf16(af[mt], bfv[nt], acc[mt][nt], 0, 0, 0);
            }
        }
    }

    __syncthreads();
    {
        int p = tid >> 1, n0 = (tid & 1) * 32;
        const float* sp = &inter[(size_t)id * 8192 + p * 64 + n0];
        #pragma unroll
        for (int k2 = 0; k2 < 4; ++k2) {
            float4 a = *reinterpret_cast<const float4*>(sp + k2 * 8);
            float4 b2 = *reinterpret_cast<const float4*>(sp + k2 * 8 + 4);
            ushort8 o;
            o[0] = f2bf(a.x); o[1] = f2bf(a.y); o[2] = f2bf(a.z); o[3] = f2bf(a.w);
            o[4] = f2bf(b2.x); o[5] = f2bf(b2.y); o[6] = f2bf(b2.z); o[7] = f2bf(b2.w);
            *reinterpret_cast<ushort8*>(&XdtT[p * 72 + n0 + k2 * 8]) = o;
        }
        int r = tid >> 1;
        int l = lh * 128 + r;
        float ef = __expf(cums[l]);
        const unsigned short* cp = &xBC[(size_t)(bc * 256 + l) * CONVDIM + DINNER + DSTATE + n0];
        #pragma unroll
        for (int k2 = 0; k2 < 4; ++k2) {
            ushort8 v = *reinterpret_cast<const ushort8*>(cp + k2 * 8);
            ushort8 o;
            #pragma unroll
            for (int j = 0; j < 8; ++j) o[j] = f2bf(bf2f(v[j]) * ef);
            *reinterpret_cast<ushort8*>(&PT[r * 72 + n0 + k2 * 8]) = o;
        }
    }
    __syncthreads();
    #pragma unroll
    for (int ks = 0; ks < 2; ++ks) {
        bf16x8 af[4], bfv[4];
        #pragma unroll
        for (int mt = 0; mt < 4; ++mt)
            af[mt] = *reinterpret_cast<const bf16x8*>(
                &PT[(wl * 64 + mt * 16 + lm) * 72 + ks * 32 + q * 8]);
        #pragma unroll
        for (int nt = 0; nt < 4; ++nt)
            bfv[nt] = *reinterpret_cast<const bf16x8*>(
                &XdtT[(wp * 64 + nt * 16 + lm) * 72 + ks * 32 + q * 8]);
        #pragma unroll
        for (int mt = 0; mt < 4; ++mt)
            #pragma unroll
            for (int nt = 0; nt < 4; ++nt)
                acc[mt][nt] = __builtin_amdgcn_mfma_f32_16x16x32_bf16(af[mt], bfv[nt], acc[mt][nt], 0, 0, 0);
    }

    #pragma unroll
    for (int mt = 0; mt < 4; ++mt)
        #pragma unroll
        for (int nt = 0; nt < 4; ++nt) {
            int l = lh * 128 + wl * 64 + mt * 16 + q * 4;
            int pcol = wp * 64 + nt * 16 + lm;
            #pragma unroll
            for (int r = 0; r < 4; ++r)
                zx[(size_t)(bc * 256 + l + r) * DINPROJ + DINNER + h * HEADDIM + pcol]
                    = f2bf(acc[mt][nt][r]);
        }
}

// ------- fused: y*silu(z) + LayerNorm  AND  out_proj_w fp32->bf16 convert -------
__global__ __launch_bounds__(256) void gate_ln_cvt(
    unsigned short* __restrict__ zx, const float* __restrict__ ln_w,
    const float* __restrict__ ln_b,
    const float* __restrict__ w2, unsigned short* __restrict__ w2_bf)
{
    __shared__ float rs[256], rq[256];
    if (blockIdx.x >= ROWS) {
        cvt8(w2, w2_bf, ((blockIdx.x - ROWS) * 256 + threadIdx.x) * 8);
        return;
    }
    int row = blockIdx.x;
    int t   = threadIdx.x;
    size_t base = (size_t)row * DINPROJ;
    float g[16];
    float sum = 0.f, sumsq = 0.f;
    #pragma unroll
    for (int j = 0; j < 2; ++j) {
        int i = t * 8 + j * 2048;
        ushort8 zv = *reinterpret_cast<const ushort8*>(zx + base + i);
        ushort8 yv = *reinterpret_cast<const ushort8*>(zx + base + DINNER + i);
        #pragma unroll
        for (int k = 0; k < 8; ++k) {
            float z = bf2f(zv[k]);
            float y = bf2f(yv[k]);
            float sig = 1.f / (1.f + __expf(-z));
            float v = y * z * sig;
            g[j * 8 + k] = v;
            sum += v; sumsq += v * v;
        }
    }
    rs[t] = sum; rq[t] = sumsq;
    __syncthreads();
    for (int off = 128; off > 0; off >>= 1) {
        if (t < off) { rs[t] += rs[t + off]; rq[t] += rq[t + off]; }
        __syncthreads();
    }
    float mu   = rs[0] * (1.f / DINNER);
    float var  = rq[0] * (1.f / DINNER) - mu * mu;
    float rstd = rsqrtf(var + 1e-5f);
    #pragma unroll
    for (int j = 0; j < 2; ++j) {
        int i = t * 8 + j * 2048;
        ushort8 o;
        #pragma unroll
        for (int k = 0; k < 8; ++k)
            o[k] = f2bf((g[j * 8 + k] - mu) * rstd * ln_w[i + k] + ln_b[i + k]);
        *reinterpret_cast<ushort8*>(zx + base + DINNER + i) = o;
    }
}

extern "C" void kernel_launch(void* const* d_in, const int* in_sizes, int n_in,
                              void* d_out, int out_size, void* d_ws, size_t ws_size,
                              hipStream_t stream)
{
    const float* u          = (const float*)d_in[0];
    const float* in_proj_w  = (const float*)d_in[1];
    const float* in_proj_b  = (const float*)d_in[2];
    const float* conv_w     = (const float*)d_in[3];
    const float* conv_b     = (const float*)d_in[4];
    const float* dt_bias    = (const float*)d_in[5];
    const float* A_log      = (const float*)d_in[6];
    const float* ln_w       = (const float*)d_in[7];
    const float* ln_b       = (const float*)d_in[8];
    const float* out_proj_w = (const float*)d_in[9];
    const float* out_proj_b = (const float*)d_in[10];
    float* out = (float*)d_out;

    // workspace layout (~238.5 MiB)
    unsigned short* zx  = (unsigned short*)d_ws;              // ROWS*DINPROJ bf16
    unsigned short* xBC = zx + (size_t)ROWS * DINPROJ;        // ROWS*CONVDIM bf16
    float* dtb    = (float*)(xBC + (size_t)ROWS * CONVDIM);   // ROWS*NHEADS f32
    float* cum    = dtb + (size_t)ROWS * NHEADS;              // ROWS*NHEADS f32
    float* csum   = cum + (size_t)ROWS * NHEADS;              // 1024 f32
    float* states = csum + 1024;                              // 1024*8192 f32
    unsigned short* S_raw = (unsigned short*)(states + (size_t)1024 * 8192); // 64*256*256 bf16

    // aliases (no live overlap):
    unsigned short* u_bf  = (unsigned short*)states;          // dead after gemm_in
    unsigned short* w1_bf = xBC;                              // dead after gemm_in
    unsigned short* w2_bf = (unsigned short*)states;          // born after y_mfma

    static bool attr_done = false;
    if (!attr_done) {
        hipFuncSetAttribute(reinterpret_cast<const void*>(&gemm256<1>),
                            hipFuncAttributeMaxDynamicSharedMemorySize, 131072);
        hipFuncSetAttribute(reinterpret_cast<const void*>(&gemm256<0>),
                            hipFuncAttributeMaxDynamicSharedMemorySize, 131072);
        attr_done = true;
    }

    dim3 blk(256);

    const int NBU  = (ROWS * DMODEL) / 2048;      // 8192
    const int NBW1 = (DINPROJ * DMODEL) / 2048;   // 8352
    f32_to_bf16_2<<<dim3(NBU + NBW1), blk, 0, stream>>>(u, u_bf, NBU, in_proj_w, w1_bf);

    gemm256<1><<<dim3((ROWS / 256) * ((DINPROJ + 255) / 256)), dim3(512), 131072, stream>>>(
        u_bf, DMODEL, w1_bf, DMODEL, in_proj_b, (void*)zx, DINPROJ, ROWS, DINPROJ, DMODEL);

    convdt<<<dim3(NCONVB + BATCH * NCHUNK * NHEADS), blk, 0, stream>>>(
        zx, conv_w, conv_b, xBC, dt_bias, A_log, dtb, cum, csum);

    score_kernel<<<dim3(BATCH * NCHUNK, 4), blk, 0, stream>>>(xBC, S_raw);

    states_kernel<<<dim3(BATCH * NCHUNK * NHEADS), blk, 0, stream>>>(xBC, dtb, cum, states);

    inter_kernel<<<dim3((BATCH * NHEADS * 8192) / 256), blk, 0, stream>>>(states, csum);

    y_mfma<<<dim3(BATCH * NCHUNK * NHEADS, 2), blk, 0, stream>>>(xBC, S_raw, dtb, cum, states, zx);

    gate_ln_cvt<<<dim3(ROWS + (DMODEL * DINNER) / 2048), blk, 0, stream>>>(
        zx, ln_w, ln_b, out_proj_w, w2_bf);

    gemm256<0><<<dim3((ROWS / 256) * (DMODEL / 256)), dim3(512), 131072, stream>>>(
        (const unsigned short*)(zx + DINNER), DINPROJ, w2_bf, DINNER, out_proj_b, (void*)out,
        DMODEL, ROWS, DMODEL, DINNER);
}